// Round 6
// baseline (787.684 us; speedup 1.0000x reference)
//
#include <hip/hip_runtime.h>
#include <math.h>

#define NN 100000
#define NE 3200000
#define FIN 512
#define NH 8
#define C1 8
#define HC1 64
#define C2 10
#define HC2 80

// radix CSR build
#define EPB 4096
#define NBLK 782           // ceil(NE/EPB)
#define NBUK 196           // ceil(NN/512)
#define SCN (NBUK * NBLK)  // 153272
#define SCNB 150           // ceil(SCN/1024)

typedef unsigned int uint;
typedef unsigned short ushort;
using bf16x8 = __attribute__((ext_vector_type(8))) short;
using f32x4  = __attribute__((ext_vector_type(4))) float;

#define RFL(x) __builtin_amdgcn_readfirstlane((int)(x))

// ---------------- static scratch ----------------
__device__ float g_h1[NN * HC1];        // x @ W1 (fp32, MFMA out)
__device__ float g_hact[NN * HC1];      // elu(agg1 + b1)
__device__ float g_h2[NN * HC2];        // hact @ W2 (fp32)
__device__ uint  g_h1b[NN * 32];        // h1 as bf16 pairs (uint k: chs 2k,2k+1)
__device__ uint  g_h2b[NN * 40];        // h2 bf16, permuted split layout (see s_kernel<2>)
__device__ uint  g_w1bt[64 * 256];      // W1 transposed bf16 pairs: [n][kp]
__device__ float g_ssrc[NN * NH];
__device__ float g_sdst[NN * NH];
__device__ int   g_off[NN + 1];
__device__ uint  g_pscan[SCN];          // per-(bucket,block) counts -> scanned
__device__ uint  g_bsum2[256];
__device__ uint  g_ebuf[NE];            // packed (dlow<<17)|src, bucket-partitioned
__device__ int   g_csr[NE];

__device__ __forceinline__ float lrelu(float x) { return fmaxf(x, 0.2f * x); }

__device__ __forceinline__ uint bf16_rne(float x) {
  uint u = __float_as_uint(x);
  u += 0x7fffu + ((u >> 16) & 1u);
  return u >> 16;
}
__device__ __forceinline__ uint packbf2(float lo, float hi) {
  return bf16_rne(lo) | (bf16_rne(hi) << 16);
}
__device__ __forceinline__ float blo(uint v) { return __uint_as_float(v << 16); }
__device__ __forceinline__ float bhi(uint v) { return __uint_as_float(v & 0xffff0000u); }

// ---------------- CSR build: radix partition by dst, no global atomics ----------
__global__ __launch_bounds__(256) void p1count_kernel(const int* __restrict__ ei) {
  __shared__ uint cnt[NBUK];
  int tid = threadIdx.x;
  for (int i = tid; i < NBUK; i += 256) cnt[i] = 0;
  __syncthreads();
  const int* dstp = ei + NE;
  int base = blockIdx.x * EPB;
#pragma unroll 4
  for (int k = 0; k < 16; k++) {
    int e = base + k * 256 + tid;
    if (e < NE) atomicAdd(&cnt[dstp[e] >> 9], 1u);
  }
  __syncthreads();
  for (int i = tid; i < NBUK; i += 256) g_pscan[i * NBLK + blockIdx.x] = cnt[i];
}

__global__ __launch_bounds__(1024) void scn_block_kernel() {
  __shared__ uint sd[1024];
  int tid = threadIdx.x;
  int i = blockIdx.x * 1024 + tid;
  uint v = (i < SCN) ? g_pscan[i] : 0;
  sd[tid] = v;
  __syncthreads();
  for (int off = 1; off < 1024; off <<= 1) {
    uint x = (tid >= off) ? sd[tid - off] : 0;
    __syncthreads();
    sd[tid] += x;
    __syncthreads();
  }
  if (i < SCN) g_pscan[i] = sd[tid] - v;  // exclusive within block
  if (tid == 1023) g_bsum2[blockIdx.x] = sd[1023];
}

__global__ void scn_tops_kernel() {  // 1 block, 256 threads
  __shared__ uint sd[256];
  int tid = threadIdx.x;
  uint v = (tid < SCNB) ? g_bsum2[tid] : 0;
  sd[tid] = v;
  __syncthreads();
  for (int off = 1; off < 256; off <<= 1) {
    uint x = (tid >= off) ? sd[tid - off] : 0;
    __syncthreads();
    sd[tid] += x;
    __syncthreads();
  }
  g_bsum2[tid] = sd[tid] - v;  // exclusive scan of block sums
}

__global__ __launch_bounds__(1024) void scn_add_kernel() {
  int i = blockIdx.x * 1024 + threadIdx.x;
  if (i < SCN) g_pscan[i] += g_bsum2[i >> 10];
}

__global__ __launch_bounds__(256) void p1scatter_kernel(const int* __restrict__ ei) {
  __shared__ uint cur[NBUK];
  int tid = threadIdx.x;
  for (int i = tid; i < NBUK; i += 256) cur[i] = g_pscan[i * NBLK + blockIdx.x];
  __syncthreads();
  const int* srcp = ei;
  const int* dstp = ei + NE;
  int base = blockIdx.x * EPB;
#pragma unroll 4
  for (int k = 0; k < 16; k++) {
    int e = base + k * 256 + tid;
    if (e < NE) {
      int d = dstp[e], s = srcp[e];
      uint pos = atomicAdd(&cur[d >> 9], 1u);  // LDS atomic
      g_ebuf[pos] = ((uint)(d & 511) << 17) | (uint)s;
    }
  }
}

// Pass 2: per-bucket 4096-bin (dlow x src-range) histogram/scan/scatter.
// Within-node edge lists come out ordered by src>>14 (8 ranges of 16K nodes)
// -> agg kernels sweep src ranges in order => XCD-L2 locality for the gathers.
__global__ __launch_bounds__(1024) void p2build_kernel() {
  __shared__ uint hist[4096];   // reused as cursors in pass 2
  __shared__ uint excl[4096];
  __shared__ uint tsum[1024];
  int tid = threadIdx.x;
  int b = blockIdx.x;
  uint bstart = g_pscan[b * NBLK];
  uint bend = (b < NBUK - 1) ? g_pscan[(b + 1) * NBLK] : NE;
  for (int i = tid; i < 4096; i += 1024) hist[i] = 0;
  __syncthreads();
  for (uint j = bstart + tid; j < bend; j += 1024) {
    uint v = g_ebuf[j];
    uint bin = ((v >> 17) << 3) | ((v & 0x1FFFFu) >> 14);
    atomicAdd(&hist[bin], 1u);
  }
  __syncthreads();
  uint h0 = hist[tid * 4 + 0], h1 = hist[tid * 4 + 1];
  uint h2 = hist[tid * 4 + 2], h3 = hist[tid * 4 + 3];
  uint s1 = h0 + h1, s2 = s1 + h2, s3 = s2 + h3;
  tsum[tid] = s3;
  __syncthreads();
  for (int off = 1; off < 1024; off <<= 1) {
    uint x = (tid >= off) ? tsum[tid - off] : 0;
    __syncthreads();
    tsum[tid] += x;
    __syncthreads();
  }
  uint te = tsum[tid] - s3;  // exclusive over threads
  excl[tid * 4 + 0] = te;
  excl[tid * 4 + 1] = te + h0;
  excl[tid * 4 + 2] = te + s1;
  excl[tid * 4 + 3] = te + s2;
  __syncthreads();
  if (tid < 512) {
    int dst = b * 512 + tid;
    if (dst < NN) g_off[dst] = (int)(bstart + excl[tid * 8]);
  }
  if (b == NBUK - 1 && tid == 0) g_off[NN] = NE;
  for (int i = tid; i < 4096; i += 1024) hist[i] = excl[i];  // cursors
  __syncthreads();
  for (uint j = bstart + tid; j < bend; j += 1024) {
    uint v = g_ebuf[j];
    uint bin = ((v >> 17) << 3) | ((v & 0x1FFFFu) >> 14);
    uint pos = bstart + atomicAdd(&hist[bin], 1u);  // LDS atomic
    g_csr[pos] = (int)(v & 0x1FFFFu);
  }
}

// ---------------- W1 -> bf16 transposed pairs ----------------
__global__ __launch_bounds__(256) void w1cast_kernel(const float* __restrict__ W) {
  int idx = blockIdx.x * 256 + threadIdx.x;  // 0..16383
  int n = idx & 63, kp = idx >> 6;           // kp 0..255
  float lo = W[(2 * kp) * HC1 + n];
  float hi = W[(2 * kp + 1) * HC1 + n];
  g_w1bt[n * 256 + kp] = packbf2(lo, hi);
}

// ---------------- GEMM1: g_h1 = X[NN,512] @ W1[512,64] via bf16 MFMA ------------
__device__ __forceinline__ int sw_idx(int row, int g) {
  return row * 32 + ((g ^ (row & 7)) << 2);
}

__global__ __launch_bounds__(256) void gemm1_kernel(const float* __restrict__ X) {
  __shared__ uint sA[64 * 32];
  __shared__ uint sB[64 * 32];
  int t = threadIdx.x;
  int w = t >> 6, l = t & 63;
  int q = l >> 4, c = l & 15;
  int r0 = blockIdx.x * 64;
  int sr = t >> 2;             // 0..63 (row / n)
  int sc = t & 3;              // quarter
  int xrow = r0 + sr; if (xrow >= NN) xrow = NN - 1;
  const float* xbase = &X[(long)xrow * FIN + sc * 16];
  const uint* wbase = &g_w1bt[sr * 256 + sc * 8];
  f32x4 acc[4] = {{0.f,0.f,0.f,0.f},{0.f,0.f,0.f,0.f},{0.f,0.f,0.f,0.f},{0.f,0.f,0.f,0.f}};
  for (int k0 = 0; k0 < FIN; k0 += 64) {
    __syncthreads();
    float4 f0 = *(const float4*)&xbase[k0 + 0];
    float4 f1 = *(const float4*)&xbase[k0 + 4];
    float4 f2 = *(const float4*)&xbase[k0 + 8];
    float4 f3 = *(const float4*)&xbase[k0 + 12];
    uint4 a0 = make_uint4(packbf2(f0.x, f0.y), packbf2(f0.z, f0.w),
                          packbf2(f1.x, f1.y), packbf2(f1.z, f1.w));
    uint4 a1 = make_uint4(packbf2(f2.x, f2.y), packbf2(f2.z, f2.w),
                          packbf2(f3.x, f3.y), packbf2(f3.z, f3.w));
    *(uint4*)&sA[sw_idx(sr, sc * 2 + 0)] = a0;
    *(uint4*)&sA[sw_idx(sr, sc * 2 + 1)] = a1;
    uint4 b0 = *(const uint4*)&wbase[(k0 >> 1) + 0];
    uint4 b1 = *(const uint4*)&wbase[(k0 >> 1) + 4];
    *(uint4*)&sB[sw_idx(sr, sc * 2 + 0)] = b0;
    *(uint4*)&sB[sw_idx(sr, sc * 2 + 1)] = b1;
    __syncthreads();
#pragma unroll
    for (int ks = 0; ks < 2; ks++) {
      int g = ks * 4 + q;
      bf16x8 a = *(const bf16x8*)&sA[sw_idx(w * 16 + c, g)];
#pragma unroll
      for (int nt = 0; nt < 4; nt++) {
        bf16x8 b = *(const bf16x8*)&sB[sw_idx(nt * 16 + c, g)];
        acc[nt] = __builtin_amdgcn_mfma_f32_16x16x32_bf16(a, b, acc[nt], 0, 0, 0);
      }
    }
  }
  int orow0 = r0 + w * 16 + q * 4;
#pragma unroll
  for (int nt = 0; nt < 4; nt++) {
#pragma unroll
    for (int r = 0; r < 4; r++) {
      int row = orow0 + r;
      if (row < NN) g_h1[row * HC1 + nt * 16 + c] = acc[nt][r];
    }
  }
}

// ---------------- attention scores + bf16 packing ----------------
// Layer 1: g_h1b uint k (0..31) = chs 2k,2k+1   (lane il reads uint2 -> chs 4il..4il+3)
// Layer 2: permuted split layout for the 4-slot agg2:
//   A (uints 0..31):  uints 2*il, 2*il+1 = chs 10*(il>>1) + 5*(il&1) + {0,1,2,3}
//   B (bytes 128..159 as 16 ushorts): ushort il = ch 10*(il>>1) + 5*(il&1) + 4
template <int LAYER>
__global__ __launch_bounds__(256) void s_kernel(const float* __restrict__ a_src,
                                                const float* __restrict__ a_dst) {
  constexpr int C = (LAYER == 1) ? C1 : C2;
  const float* Hm = (LAYER == 1) ? g_h1 : g_h2;
  int t = blockIdx.x * 256 + threadIdx.x;
  if (t >= NN * NH) return;
  int h = t & 7;
  const float* row = &Hm[t * C];
  float ss = 0.f, sdd = 0.f;
  float vals[C];
#pragma unroll
  for (int c = 0; c < C; c++) {
    float v = row[c];
    vals[c] = v;
    ss = fmaf(v, a_src[h * C + c], ss);
    sdd = fmaf(v, a_dst[h * C + c], sdd);
  }
  g_ssrc[t] = ss;
  g_sdst[t] = sdd;
  if constexpr (LAYER == 1) {
#pragma unroll
    for (int j = 0; j < 4; j++)
      g_h1b[t * 4 + j] = packbf2(vals[2 * j], vals[2 * j + 1]);
  } else {
    int n = t >> 3;
#pragma unroll
    for (int b = 0; b < 2; b++) {
      int il = 2 * h + b;
      g_h2b[n * 40 + 2 * il + 0] = packbf2(vals[5 * b + 0], vals[5 * b + 1]);
      g_h2b[n * 40 + 2 * il + 1] = packbf2(vals[5 * b + 2], vals[5 * b + 3]);
      ((ushort*)&g_h2b[n * 40 + 32])[il] = (ushort)bf16_rne(vals[5 * b + 4]);
    }
  }
}

// ---- layer-1 aggregation: wave/node, 4 edge-slots x 16 lanes x 4 channels ----
// 4 independent chains (16 edges/iter): per-lane csr index loads (no RFL
// serialization) -> ~12-16 outstanding gathers per wave for latency hiding.
__global__ __launch_bounds__(256) void agg1_kernel(const float* __restrict__ b1) {
  int gw = RFL((blockIdx.x * 256 + threadIdx.x) >> 6);
  if (gw >= NN) return;
  int lane = threadIdx.x & 63;
  int sl = lane >> 4, il = lane & 15;
  int hh = il >> 1;
  float sdl = g_sdst[gw * NH + hh];
  float4 bb = *(const float4*)&b1[4 * il];
  int j = g_off[gw];
  int jend = g_off[gw + 1];
  if (jend < j) jend = j;  // defensive clamp
  float a0A=0.f,a1A=0.f,a2A=0.f,a3A=0.f,wA=0.f;
  float a0B=0.f,a1B=0.f,a2B=0.f,a3B=0.f,wB=0.f;
  float a0C=0.f,a1C=0.f,a2C=0.f,a3C=0.f,wC=0.f;
  float a0D=0.f,a1D=0.f,a2D=0.f,a3D=0.f,wD=0.f;
#define G1(IDX,A0,A1,A2,A3,WW) {                                     \
    float tt = g_ssrc[(IDX) * NH + hh];                              \
    uint2 va = *(const uint2*)&g_h1b[(IDX) * 32 + 2 * il];           \
    float e = __expf(lrelu(tt + sdl));                               \
    A0 = fmaf(blo(va.x), e, A0); A1 = fmaf(bhi(va.x), e, A1);        \
    A2 = fmaf(blo(va.y), e, A2); A3 = fmaf(bhi(va.y), e, A3);        \
    WW += e; }
  for (; j + 16 <= jend; j += 16) {
    int i0 = g_csr[j + sl];
    int i1 = g_csr[j + 4 + sl];
    int i2 = g_csr[j + 8 + sl];
    int i3 = g_csr[j + 12 + sl];
    G1(i0, a0A, a1A, a2A, a3A, wA)
    G1(i1, a0B, a1B, a2B, a3B, wB)
    G1(i2, a0C, a1C, a2C, a3C, wC)
    G1(i3, a0D, a1D, a2D, a3D, wD)
  }
  for (; j + 4 <= jend; j += 4) {
    int i0 = g_csr[j + sl];
    G1(i0, a0A, a1A, a2A, a3A, wA)
  }
#undef G1
  int rem = jend - j;
  if (rem > 0) {  // masked one-shot tail (<=3 edges)
    int i0 = g_csr[j + (sl < rem ? sl : 0)];
    float tt = g_ssrc[i0 * NH + hh];
    uint2 va = *(const uint2*)&g_h1b[i0 * 32 + 2 * il];
    float e = (sl < rem) ? __expf(lrelu(tt + sdl)) : 0.f;
    a0B = fmaf(blo(va.x), e, a0B); a1B = fmaf(bhi(va.x), e, a1B);
    a2B = fmaf(blo(va.y), e, a2B); a3B = fmaf(bhi(va.y), e, a3B);
    wB += e;
  }
  float a0 = (a0A + a0B) + (a0C + a0D);
  float a1 = (a1A + a1B) + (a1C + a1D);
  float a2 = (a2A + a2B) + (a2C + a2D);
  float a3 = (a3A + a3B) + (a3C + a3D);
  float w  = (wA + wB) + (wC + wD);
  a0 += __shfl_xor(a0, 16); a0 += __shfl_xor(a0, 32);
  a1 += __shfl_xor(a1, 16); a1 += __shfl_xor(a1, 32);
  a2 += __shfl_xor(a2, 16); a2 += __shfl_xor(a2, 32);
  a3 += __shfl_xor(a3, 16); a3 += __shfl_xor(a3, 32);
  w  += __shfl_xor(w, 16);  w  += __shfl_xor(w, 32);
  float es = __expf(lrelu(g_ssrc[gw * NH + hh] + sdl));
  float4 hv = *(const float4*)&g_h1[gw * HC1 + 4 * il];  // self loop fp32
  a0 = fmaf(hv.x, es, a0); a1 = fmaf(hv.y, es, a1);
  a2 = fmaf(hv.z, es, a2); a3 = fmaf(hv.w, es, a3);
  w += es;
  float inv = 1.f / w;
  float v0 = a0 * inv + bb.x, v1 = a1 * inv + bb.y;
  float v2 = a2 * inv + bb.z, v3 = a3 * inv + bb.w;
  v0 = v0 > 0.f ? v0 : __expf(v0) - 1.f;
  v1 = v1 > 0.f ? v1 : __expf(v1) - 1.f;
  v2 = v2 > 0.f ? v2 : __expf(v2) - 1.f;
  v3 = v3 > 0.f ? v3 : __expf(v3) - 1.f;
  if (sl == 0) *(float4*)&g_hact[gw * HC1 + 4 * il] = make_float4(v0, v1, v2, v3);
}

// ---------------- GEMM2: g_h2 = g_hact[NN,64] @ W2[64,80] ----------------
__global__ __launch_bounds__(256) void gemm2_kernel(const float* __restrict__ W) {
  __shared__ float sW[64 * HC2 + 64];
  int tid = threadIdx.x;
  for (int i = tid; i < 64 * HC2; i += 256) sW[i] = W[i];
  for (int i = 64 * HC2 + tid; i < 64 * HC2 + 64; i += 256) sW[i] = 0.f;
  __syncthreads();
  int lane = tid & 63;
  int w0 = (blockIdx.x * 256 + tid) >> 6;
  for (int r = w0; r < NN; r += 8192) {
    float v = g_hact[r * HC1 + lane];
    float acc0 = 0.f, acc1 = 0.f;
#pragma unroll
    for (int k = 0; k < 64; k++) {
      float xk = __shfl(v, k);
      acc0 = fmaf(xk, sW[k * HC2 + lane], acc0);
      acc1 = fmaf(xk, sW[k * HC2 + 64 + lane], acc1);
    }
    g_h2[r * HC2 + lane] = acc0;
    if (lane < 16) g_h2[r * HC2 + 64 + lane] = acc1;
  }
}

// ---- layer-2 aggregation: 4 edge-slots x 16 lanes x 5 channels + log_softmax --
__global__ __launch_bounds__(256) void agg2_kernel(float* __restrict__ out,
                                                   const float* __restrict__ b2) {
  int gw = RFL((blockIdx.x * 256 + threadIdx.x) >> 6);
  if (gw >= NN) return;
  int lane = threadIdx.x & 63;
  int sl = lane >> 4, il = lane & 15;
  int hh = il >> 1, bq = il & 1;
  int c0 = 10 * hh + 5 * bq;  // first true channel of this lane
  float sdl = g_sdst[gw * NH + hh];
  float bb0 = b2[c0 + 0], bb1 = b2[c0 + 1], bb2 = b2[c0 + 2];
  float bb3 = b2[c0 + 3], bb4 = b2[c0 + 4];
  int j = g_off[gw];
  int jend = g_off[gw + 1];
  if (jend < j) jend = j;  // defensive clamp
  float a0A=0.f,a1A=0.f,a2A=0.f,a3A=0.f,a4A=0.f,wA=0.f;
  float a0B=0.f,a1B=0.f,a2B=0.f,a3B=0.f,a4B=0.f,wB=0.f;
  float a0C=0.f,a1C=0.f,a2C=0.f,a3C=0.f,a4C=0.f,wC=0.f;
  float a0D=0.f,a1D=0.f,a2D=0.f,a3D=0.f,a4D=0.f,wD=0.f;
#define G2(IDX,A0,A1,A2,A3,A4,WW) {                                  \
    float tt = g_ssrc[(IDX) * NH + hh];                              \
    uint2 va = *(const uint2*)&g_h2b[(IDX) * 40 + 2 * il];           \
    uint vb = ((const ushort*)&g_h2b[(IDX) * 40 + 32])[il];          \
    float e = __expf(lrelu(tt + sdl));                               \
    A0 = fmaf(blo(va.x), e, A0); A1 = fmaf(bhi(va.x), e, A1);        \
    A2 = fmaf(blo(va.y), e, A2); A3 = fmaf(bhi(va.y), e, A3);        \
    A4 = fmaf(__uint_as_float(vb << 16), e, A4);                     \
    WW += e; }
  for (; j + 16 <= jend; j += 16) {
    int i0 = g_csr[j + sl];
    int i1 = g_csr[j + 4 + sl];
    int i2 = g_csr[j + 8 + sl];
    int i3 = g_csr[j + 12 + sl];
    G2(i0, a0A, a1A, a2A, a3A, a4A, wA)
    G2(i1, a0B, a1B, a2B, a3B, a4B, wB)
    G2(i2, a0C, a1C, a2C, a3C, a4C, wC)
    G2(i3, a0D, a1D, a2D, a3D, a4D, wD)
  }
  for (; j + 4 <= jend; j += 4) {
    int i0 = g_csr[j + sl];
    G2(i0, a0A, a1A, a2A, a3A, a4A, wA)
  }
#undef G2
  int rem = jend - j;
  if (rem > 0) {  // masked one-shot tail (<=3 edges)
    int i0 = g_csr[j + (sl < rem ? sl : 0)];
    float tt = g_ssrc[i0 * NH + hh];
    uint2 va = *(const uint2*)&g_h2b[i0 * 40 + 2 * il];
    uint vb = ((const ushort*)&g_h2b[i0 * 40 + 32])[il];
    float e = (sl < rem) ? __expf(lrelu(tt + sdl)) : 0.f;
    a0B = fmaf(blo(va.x), e, a0B); a1B = fmaf(bhi(va.x), e, a1B);
    a2B = fmaf(blo(va.y), e, a2B); a3B = fmaf(bhi(va.y), e, a3B);
    a4B = fmaf(__uint_as_float(vb << 16), e, a4B);
    wB += e;
  }
  float a0 = (a0A + a0B) + (a0C + a0D);
  float a1 = (a1A + a1B) + (a1C + a1D);
  float a2 = (a2A + a2B) + (a2C + a2D);
  float a3 = (a3A + a3B) + (a3C + a3D);
  float a4 = (a4A + a4B) + (a4C + a4D);
  float w  = (wA + wB) + (wC + wD);
  a0 += __shfl_xor(a0, 16); a0 += __shfl_xor(a0, 32);
  a1 += __shfl_xor(a1, 16); a1 += __shfl_xor(a1, 32);
  a2 += __shfl_xor(a2, 16); a2 += __shfl_xor(a2, 32);
  a3 += __shfl_xor(a3, 16); a3 += __shfl_xor(a3, 32);
  a4 += __shfl_xor(a4, 16); a4 += __shfl_xor(a4, 32);
  w  += __shfl_xor(w, 16);  w  += __shfl_xor(w, 32);
  float es = __expf(lrelu(g_ssrc[gw * NH + hh] + sdl));
  const float* h2row = &g_h2[gw * HC2 + c0];  // self loop fp32
  a0 = fmaf(h2row[0], es, a0); a1 = fmaf(h2row[1], es, a1);
  a2 = fmaf(h2row[2], es, a2); a3 = fmaf(h2row[3], es, a3);
  a4 = fmaf(h2row[4], es, a4);
  w += es;
  float inv = 1.f / w;
  float v0 = a0 * inv + bb0, v1 = a1 * inv + bb1, v2 = a2 * inv + bb2;
  float v3 = a3 * inv + bb3, v4 = a4 * inv + bb4;
  // log_softmax over the 80 chs spread across the 16-lane group
  float mx = fmaxf(fmaxf(fmaxf(v0, v1), fmaxf(v2, v3)), v4);
  for (int o = 1; o < 16; o <<= 1) mx = fmaxf(mx, __shfl_xor(mx, o));
  float sp = __expf(v0 - mx) + __expf(v1 - mx) + __expf(v2 - mx) +
             __expf(v3 - mx) + __expf(v4 - mx);
  for (int o = 1; o < 16; o <<= 1) sp += __shfl_xor(sp, o);
  float lse = mx + __logf(sp);
  if (sl == 0) {
    float* op = &out[gw * HC2 + c0];
    op[0] = v0 - lse; op[1] = v1 - lse; op[2] = v2 - lse;
    op[3] = v3 - lse; op[4] = v4 - lse;
  }
}

// ---------------- launch ----------------
extern "C" void kernel_launch(void* const* d_in, const int* in_sizes, int n_in,
                              void* d_out, int out_size, void* d_ws, size_t ws_size,
                              hipStream_t stream) {
  (void)in_sizes; (void)n_in; (void)out_size; (void)d_ws; (void)ws_size;
  const float* x   = (const float*)d_in[0];
  const int*   ei  = (const int*)d_in[1];
  const float* W1  = (const float*)d_in[2];
  const float* as1 = (const float*)d_in[3];
  const float* ad1 = (const float*)d_in[4];
  const float* b1  = (const float*)d_in[5];
  const float* W2  = (const float*)d_in[6];
  const float* as2 = (const float*)d_in[7];
  const float* ad2 = (const float*)d_in[8];
  const float* b2  = (const float*)d_in[9];
  float* out = (float*)d_out;

  // CSR build (radix partition + src-range ordering; shared by both layers)
  p1count_kernel<<<NBLK, 256, 0, stream>>>(ei);
  scn_block_kernel<<<SCNB, 1024, 0, stream>>>();
  scn_tops_kernel<<<1, 256, 0, stream>>>();
  scn_add_kernel<<<SCNB, 1024, 0, stream>>>();
  p1scatter_kernel<<<NBLK, 256, 0, stream>>>(ei);
  p2build_kernel<<<NBUK, 1024, 0, stream>>>();

  // layer 1
  w1cast_kernel<<<64, 256, 0, stream>>>(W1);
  gemm1_kernel<<<1563, 256, 0, stream>>>(x);
  s_kernel<1><<<3125, 256, 0, stream>>>(as1, ad1);
  agg1_kernel<<<25000, 256, 0, stream>>>(b1);

  // layer 2
  gemm2_kernel<<<2048, 256, 0, stream>>>(W2);
  s_kernel<2><<<3125, 256, 0, stream>>>(as2, ad2);
  agg2_kernel<<<25000, 256, 0, stream>>>(out, b2);
}

// Round 7
// 778.250 us; speedup vs baseline: 1.0121x; 1.0121x over previous
//
#include <hip/hip_runtime.h>
#include <math.h>

#define NN 100000
#define NE 3200000
#define FIN 512
#define NH 8
#define C1 8
#define HC1 64
#define C2 10
#define HC2 80

// radix CSR build
#define EPB 4096
#define NBLK 782           // ceil(NE/EPB)
#define NBUK 196           // ceil(NN/512)
#define SCN (NBUK * NBLK)  // 153272
#define SCNB 150           // ceil(SCN/1024)

typedef unsigned int uint;
typedef unsigned short ushort;
using bf16x8 = __attribute__((ext_vector_type(8))) short;
using f32x4  = __attribute__((ext_vector_type(4))) float;

#define RFL(x) __builtin_amdgcn_readfirstlane((int)(x))

// ---------------- static scratch ----------------
__device__ float g_h1[NN * HC1];        // x @ W1 (fp32, MFMA out)
__device__ float g_hact[NN * HC1];      // elu(agg1 + b1)
__device__ float g_h2[NN * HC2];        // hact @ W2 (fp32)
__device__ uint  g_h1b[NN * 32];        // h1 as bf16 pairs (uint k: chs 2k,2k+1)
__device__ uint  g_h2b[NN * 48];        // layer-2 combined row, 192B aligned:
                                        //   uints 0..31  : bf16 feature pairs (permuted split A)
                                        //   uints 32..39 : 16 ushort bf16 (split B, ch .. +4)
                                        //   uints 40..47 : fp32 ssrc[8 heads]
__device__ uint  g_w1bt[64 * 256];      // W1 transposed bf16 pairs: [n][kp]
__device__ float g_ssrc[NN * NH];       // layer-1 src scores
__device__ float g_sdst[NN * NH];
__device__ int   g_off[NN + 1];
__device__ uint  g_pscan[SCN];          // per-(bucket,block) counts -> scanned
__device__ uint  g_bsum2[256];
__device__ uint  g_ebuf[NE];            // packed (dlow<<17)|src, bucket-partitioned
__device__ int   g_csr[NE];

__device__ __forceinline__ float lrelu(float x) { return fmaxf(x, 0.2f * x); }

__device__ __forceinline__ uint bf16_rne(float x) {
  uint u = __float_as_uint(x);
  u += 0x7fffu + ((u >> 16) & 1u);
  return u >> 16;
}
__device__ __forceinline__ uint packbf2(float lo, float hi) {
  return bf16_rne(lo) | (bf16_rne(hi) << 16);
}
__device__ __forceinline__ float blo(uint v) { return __uint_as_float(v << 16); }
__device__ __forceinline__ float bhi(uint v) { return __uint_as_float(v & 0xffff0000u); }

// ---------------- CSR build: radix partition by dst, no global atomics ----------
__global__ __launch_bounds__(256) void p1count_kernel(const int* __restrict__ ei) {
  __shared__ uint cnt[NBUK];
  int tid = threadIdx.x;
  for (int i = tid; i < NBUK; i += 256) cnt[i] = 0;
  __syncthreads();
  const int* dstp = ei + NE;
  int base = blockIdx.x * EPB;
#pragma unroll 4
  for (int k = 0; k < 16; k++) {
    int e = base + k * 256 + tid;
    if (e < NE) atomicAdd(&cnt[dstp[e] >> 9], 1u);
  }
  __syncthreads();
  for (int i = tid; i < NBUK; i += 256) g_pscan[i * NBLK + blockIdx.x] = cnt[i];
}

__global__ __launch_bounds__(1024) void scn_block_kernel() {
  __shared__ uint sd[1024];
  int tid = threadIdx.x;
  int i = blockIdx.x * 1024 + tid;
  uint v = (i < SCN) ? g_pscan[i] : 0;
  sd[tid] = v;
  __syncthreads();
  for (int off = 1; off < 1024; off <<= 1) {
    uint x = (tid >= off) ? sd[tid - off] : 0;
    __syncthreads();
    sd[tid] += x;
    __syncthreads();
  }
  if (i < SCN) g_pscan[i] = sd[tid] - v;  // exclusive within block
  if (tid == 1023) g_bsum2[blockIdx.x] = sd[1023];
}

// scn_add with the top-level scan folded in: each block redundantly scans the
// 150 block sums in LDS (removes the serial 1-block scn_tops launch).
__global__ __launch_bounds__(1024) void scn_add_kernel() {
  __shared__ uint sums[256];
  __shared__ uint ex[256];
  int tid = threadIdx.x;
  uint orig = 0;
  if (tid < 256) {
    orig = (tid < SCNB) ? g_bsum2[tid] : 0;
    sums[tid] = orig;
  }
  __syncthreads();
  for (int off = 1; off < 256; off <<= 1) {
    uint x = 0;
    if (tid < 256 && tid >= off) x = sums[tid - off];
    __syncthreads();
    if (tid < 256) sums[tid] += x;
    __syncthreads();
  }
  if (tid < 256) ex[tid] = sums[tid] - orig;  // exclusive
  __syncthreads();
  uint add = ex[blockIdx.x];
  int i = blockIdx.x * 1024 + tid;
  if (i < SCN) g_pscan[i] += add;
}

__global__ __launch_bounds__(256) void p1scatter_kernel(const int* __restrict__ ei) {
  __shared__ uint cur[NBUK];
  int tid = threadIdx.x;
  for (int i = tid; i < NBUK; i += 256) cur[i] = g_pscan[i * NBLK + blockIdx.x];
  __syncthreads();
  const int* srcp = ei;
  const int* dstp = ei + NE;
  int base = blockIdx.x * EPB;
#pragma unroll 4
  for (int k = 0; k < 16; k++) {
    int e = base + k * 256 + tid;
    if (e < NE) {
      int d = dstp[e], s = srcp[e];
      uint pos = atomicAdd(&cur[d >> 9], 1u);  // LDS atomic
      g_ebuf[pos] = ((uint)(d & 511) << 17) | (uint)s;
    }
  }
}

// Pass 2: per-bucket 4096-bin (dlow x src-range) histogram/scan/scatter.
// Within-node edge lists come out ordered by src>>14 (8 ranges of 16K nodes)
// -> agg kernels sweep src ranges in order => XCD-L2 locality for the gathers.
__global__ __launch_bounds__(1024) void p2build_kernel() {
  __shared__ uint hist[4096];   // reused as cursors in pass 2
  __shared__ uint excl[4096];
  __shared__ uint tsum[1024];
  int tid = threadIdx.x;
  int b = blockIdx.x;
  uint bstart = g_pscan[b * NBLK];
  uint bend = (b < NBUK - 1) ? g_pscan[(b + 1) * NBLK] : NE;
  for (int i = tid; i < 4096; i += 1024) hist[i] = 0;
  __syncthreads();
  for (uint j = bstart + tid; j < bend; j += 1024) {
    uint v = g_ebuf[j];
    uint bin = ((v >> 17) << 3) | ((v & 0x1FFFFu) >> 14);
    atomicAdd(&hist[bin], 1u);
  }
  __syncthreads();
  uint h0 = hist[tid * 4 + 0], h1 = hist[tid * 4 + 1];
  uint h2 = hist[tid * 4 + 2], h3 = hist[tid * 4 + 3];
  uint s1 = h0 + h1, s2 = s1 + h2, s3 = s2 + h3;
  tsum[tid] = s3;
  __syncthreads();
  for (int off = 1; off < 1024; off <<= 1) {
    uint x = (tid >= off) ? tsum[tid - off] : 0;
    __syncthreads();
    tsum[tid] += x;
    __syncthreads();
  }
  uint te = tsum[tid] - s3;  // exclusive over threads
  excl[tid * 4 + 0] = te;
  excl[tid * 4 + 1] = te + h0;
  excl[tid * 4 + 2] = te + s1;
  excl[tid * 4 + 3] = te + s2;
  __syncthreads();
  if (tid < 512) {
    int dst = b * 512 + tid;
    if (dst < NN) g_off[dst] = (int)(bstart + excl[tid * 8]);
  }
  if (b == NBUK - 1 && tid == 0) g_off[NN] = NE;
  for (int i = tid; i < 4096; i += 1024) hist[i] = excl[i];  // cursors
  __syncthreads();
  for (uint j = bstart + tid; j < bend; j += 1024) {
    uint v = g_ebuf[j];
    uint bin = ((v >> 17) << 3) | ((v & 0x1FFFFu) >> 14);
    uint pos = bstart + atomicAdd(&hist[bin], 1u);  // LDS atomic
    g_csr[pos] = (int)(v & 0x1FFFFu);
  }
}

// ---------------- W1 -> bf16 transposed pairs ----------------
__global__ __launch_bounds__(256) void w1cast_kernel(const float* __restrict__ W) {
  int idx = blockIdx.x * 256 + threadIdx.x;  // 0..16383
  int n = idx & 63, kp = idx >> 6;           // kp 0..255
  float lo = W[(2 * kp) * HC1 + n];
  float hi = W[(2 * kp + 1) * HC1 + n];
  g_w1bt[n * 256 + kp] = packbf2(lo, hi);
}

// ---------------- GEMM1: g_h1 = X[NN,512] @ W1[512,64] via bf16 MFMA ------------
__device__ __forceinline__ int sw_idx(int row, int g) {
  return row * 32 + ((g ^ (row & 7)) << 2);
}

__global__ __launch_bounds__(256) void gemm1_kernel(const float* __restrict__ X) {
  __shared__ uint sA[64 * 32];
  __shared__ uint sB[64 * 32];
  int t = threadIdx.x;
  int w = t >> 6, l = t & 63;
  int q = l >> 4, c = l & 15;
  int r0 = blockIdx.x * 64;
  int sr = t >> 2;             // 0..63 (row / n)
  int sc = t & 3;              // quarter
  int xrow = r0 + sr; if (xrow >= NN) xrow = NN - 1;
  const float* xbase = &X[(long)xrow * FIN + sc * 16];
  const uint* wbase = &g_w1bt[sr * 256 + sc * 8];
  f32x4 acc[4] = {{0.f,0.f,0.f,0.f},{0.f,0.f,0.f,0.f},{0.f,0.f,0.f,0.f},{0.f,0.f,0.f,0.f}};
  for (int k0 = 0; k0 < FIN; k0 += 64) {
    __syncthreads();
    float4 f0 = *(const float4*)&xbase[k0 + 0];
    float4 f1 = *(const float4*)&xbase[k0 + 4];
    float4 f2 = *(const float4*)&xbase[k0 + 8];
    float4 f3 = *(const float4*)&xbase[k0 + 12];
    uint4 a0 = make_uint4(packbf2(f0.x, f0.y), packbf2(f0.z, f0.w),
                          packbf2(f1.x, f1.y), packbf2(f1.z, f1.w));
    uint4 a1 = make_uint4(packbf2(f2.x, f2.y), packbf2(f2.z, f2.w),
                          packbf2(f3.x, f3.y), packbf2(f3.z, f3.w));
    *(uint4*)&sA[sw_idx(sr, sc * 2 + 0)] = a0;
    *(uint4*)&sA[sw_idx(sr, sc * 2 + 1)] = a1;
    uint4 b0 = *(const uint4*)&wbase[(k0 >> 1) + 0];
    uint4 b1 = *(const uint4*)&wbase[(k0 >> 1) + 4];
    *(uint4*)&sB[sw_idx(sr, sc * 2 + 0)] = b0;
    *(uint4*)&sB[sw_idx(sr, sc * 2 + 1)] = b1;
    __syncthreads();
#pragma unroll
    for (int ks = 0; ks < 2; ks++) {
      int g = ks * 4 + q;
      bf16x8 a = *(const bf16x8*)&sA[sw_idx(w * 16 + c, g)];
#pragma unroll
      for (int nt = 0; nt < 4; nt++) {
        bf16x8 b = *(const bf16x8*)&sB[sw_idx(nt * 16 + c, g)];
        acc[nt] = __builtin_amdgcn_mfma_f32_16x16x32_bf16(a, b, acc[nt], 0, 0, 0);
      }
    }
  }
  int orow0 = r0 + w * 16 + q * 4;
#pragma unroll
  for (int nt = 0; nt < 4; nt++) {
#pragma unroll
    for (int r = 0; r < 4; r++) {
      int row = orow0 + r;
      if (row < NN) g_h1[row * HC1 + nt * 16 + c] = acc[nt][r];
    }
  }
}

// ---------------- attention scores + bf16 packing ----------------
// Layer 1: g_h1b uint k (0..31) = chs 2k,2k+1 (lane il reads uint2 -> chs 4il..4il+3)
//          scores to g_ssrc (separate gather stream; already at its 3-line floor).
// Layer 2: combined 192B row in g_h2b (48 uints):
//   A (uints 0..31):  uints 2*il, 2*il+1 = chs 10*(il>>1) + 5*(il&1) + {0,1,2,3}
//   B (uints 32..39 as 16 ushorts): ushort il = ch 10*(il>>1) + 5*(il&1) + 4
//   scores (uints 40..47): fp32 ssrc[head]  -> whole row = exactly 3 cachelines
template <int LAYER>
__global__ __launch_bounds__(256) void s_kernel(const float* __restrict__ a_src,
                                                const float* __restrict__ a_dst) {
  constexpr int C = (LAYER == 1) ? C1 : C2;
  const float* Hm = (LAYER == 1) ? g_h1 : g_h2;
  int t = blockIdx.x * 256 + threadIdx.x;
  if (t >= NN * NH) return;
  int h = t & 7;
  const float* row = &Hm[t * C];
  float ss = 0.f, sdd = 0.f;
  float vals[C];
#pragma unroll
  for (int c = 0; c < C; c++) {
    float v = row[c];
    vals[c] = v;
    ss = fmaf(v, a_src[h * C + c], ss);
    sdd = fmaf(v, a_dst[h * C + c], sdd);
  }
  g_sdst[t] = sdd;
  if constexpr (LAYER == 1) {
    g_ssrc[t] = ss;
#pragma unroll
    for (int j = 0; j < 4; j++)
      g_h1b[t * 4 + j] = packbf2(vals[2 * j], vals[2 * j + 1]);
  } else {
    int n = t >> 3;
#pragma unroll
    for (int b = 0; b < 2; b++) {
      int il = 2 * h + b;
      g_h2b[n * 48 + 2 * il + 0] = packbf2(vals[5 * b + 0], vals[5 * b + 1]);
      g_h2b[n * 48 + 2 * il + 1] = packbf2(vals[5 * b + 2], vals[5 * b + 3]);
      ((ushort*)&g_h2b[n * 48 + 32])[il] = (ushort)bf16_rne(vals[5 * b + 4]);
    }
    g_h2b[n * 48 + 40 + h] = __float_as_uint(ss);  // embedded fp32 score
  }
}

// ---- layer-1 aggregation: wave/node, 4 edge-slots x 16 lanes x 4 channels ----
// Per 4 edges: 1 exp, 1 score chain, 4 fma (all 64 lanes useful). Slot partials
// merged by shfl_xor(16/32) butterfly. Two register chains (A/B) for MLP.
__global__ __launch_bounds__(256) void agg1_kernel(const float* __restrict__ b1) {
  int gw = RFL((blockIdx.x * 256 + threadIdx.x) >> 6);
  if (gw >= NN) return;
  int lane = threadIdx.x & 63;
  int sl = lane >> 4, il = lane & 15;
  int hh = il >> 1;
  bool sl1 = (sl & 1) != 0, sl2 = (sl & 2) != 0;
  float sdl = g_sdst[gw * NH + hh];
  float4 bb = *(const float4*)&b1[4 * il];
  int j = g_off[gw];
  int jend = g_off[gw + 1];
  if (jend < j) jend = j;  // defensive clamp
  float a0A=0.f,a1A=0.f,a2A=0.f,a3A=0.f,wA=0.f;
  float a0B=0.f,a1B=0.f,a2B=0.f,a3B=0.f,wB=0.f;
#define G1(A0,A1,A2,A3,WW,J) {                                       \
    int s0 = RFL(g_csr[(J)+0]), s1 = RFL(g_csr[(J)+1]);              \
    int s2 = RFL(g_csr[(J)+2]), s3 = RFL(g_csr[(J)+3]);              \
    int ssx = sl2 ? (sl1 ? s3 : s2) : (sl1 ? s1 : s0);               \
    float tt = g_ssrc[ssx * NH + hh];                                \
    uint2 va = *(const uint2*)&g_h1b[ssx * 32 + 2 * il];             \
    float e = __expf(lrelu(tt + sdl));                               \
    A0 = fmaf(blo(va.x), e, A0); A1 = fmaf(bhi(va.x), e, A1);        \
    A2 = fmaf(blo(va.y), e, A2); A3 = fmaf(bhi(va.y), e, A3);        \
    WW += e; }
  for (; j + 8 <= jend; j += 8) {
    G1(a0A,a1A,a2A,a3A,wA,j)
    G1(a0B,a1B,a2B,a3B,wB,j+4)
  }
  if (j + 4 <= jend) { G1(a0A,a1A,a2A,a3A,wA,j); j += 4; }
#undef G1
  // robust per-edge tail (<=3 iters): slot 0 accumulates, others add 0
  for (; j < jend; j++) {
    int s0 = RFL(g_csr[j]);
    float tt = g_ssrc[s0 * NH + hh];
    uint2 va = *(const uint2*)&g_h1b[s0 * 32 + 2 * il];
    float e = (sl == 0) ? __expf(lrelu(tt + sdl)) : 0.f;
    a0B = fmaf(blo(va.x), e, a0B); a1B = fmaf(bhi(va.x), e, a1B);
    a2B = fmaf(blo(va.y), e, a2B); a3B = fmaf(bhi(va.y), e, a3B);
    wB += e;
  }
  float a0 = a0A + a0B, a1 = a1A + a1B, a2 = a2A + a2B, a3 = a3A + a3B;
  float w = wA + wB;
  a0 += __shfl_xor(a0, 16); a0 += __shfl_xor(a0, 32);
  a1 += __shfl_xor(a1, 16); a1 += __shfl_xor(a1, 32);
  a2 += __shfl_xor(a2, 16); a2 += __shfl_xor(a2, 32);
  a3 += __shfl_xor(a3, 16); a3 += __shfl_xor(a3, 32);
  w  += __shfl_xor(w, 16);  w  += __shfl_xor(w, 32);
  float es = __expf(lrelu(g_ssrc[gw * NH + hh] + sdl));
  float4 hv = *(const float4*)&g_h1[gw * HC1 + 4 * il];  // self loop fp32
  a0 = fmaf(hv.x, es, a0); a1 = fmaf(hv.y, es, a1);
  a2 = fmaf(hv.z, es, a2); a3 = fmaf(hv.w, es, a3);
  w += es;
  float inv = 1.f / w;
  float v0 = a0 * inv + bb.x, v1 = a1 * inv + bb.y;
  float v2 = a2 * inv + bb.z, v3 = a3 * inv + bb.w;
  v0 = v0 > 0.f ? v0 : __expf(v0) - 1.f;
  v1 = v1 > 0.f ? v1 : __expf(v1) - 1.f;
  v2 = v2 > 0.f ? v2 : __expf(v2) - 1.f;
  v3 = v3 > 0.f ? v3 : __expf(v3) - 1.f;
  if (sl == 0) *(float4*)&g_hact[gw * HC1 + 4 * il] = make_float4(v0, v1, v2, v3);
}

// ---------------- GEMM2: g_h2 = g_hact[NN,64] @ W2[64,80] ----------------
__global__ __launch_bounds__(256) void gemm2_kernel(const float* __restrict__ W) {
  __shared__ float sW[64 * HC2 + 64];
  int tid = threadIdx.x;
  for (int i = tid; i < 64 * HC2; i += 256) sW[i] = W[i];
  for (int i = 64 * HC2 + tid; i < 64 * HC2 + 64; i += 256) sW[i] = 0.f;
  __syncthreads();
  int lane = tid & 63;
  int w0 = (blockIdx.x * 256 + tid) >> 6;
  for (int r = w0; r < NN; r += 8192) {
    float v = g_hact[r * HC1 + lane];
    float acc0 = 0.f, acc1 = 0.f;
#pragma unroll
    for (int k = 0; k < 64; k++) {
      float xk = __shfl(v, k);
      acc0 = fmaf(xk, sW[k * HC2 + lane], acc0);
      acc1 = fmaf(xk, sW[k * HC2 + 64 + lane], acc1);
    }
    g_h2[r * HC2 + lane] = acc0;
    if (lane < 16) g_h2[r * HC2 + 64 + lane] = acc1;
  }
}

// ---- layer-2 aggregation: 4 edge-slots x 16 lanes x 5 channels + log_softmax --
// Combined 192B row (features + embedded fp32 scores) => 3 cachelines/edge.
__global__ __launch_bounds__(256) void agg2_kernel(float* __restrict__ out,
                                                   const float* __restrict__ b2) {
  int gw = RFL((blockIdx.x * 256 + threadIdx.x) >> 6);
  if (gw >= NN) return;
  int lane = threadIdx.x & 63;
  int sl = lane >> 4, il = lane & 15;
  int hh = il >> 1, bq = il & 1;
  int c0 = 10 * hh + 5 * bq;  // first true channel of this lane
  bool sl1 = (sl & 1) != 0, sl2 = (sl & 2) != 0;
  float sdl = g_sdst[gw * NH + hh];
  float bb0 = b2[c0 + 0], bb1 = b2[c0 + 1], bb2 = b2[c0 + 2];
  float bb3 = b2[c0 + 3], bb4 = b2[c0 + 4];
  int j = g_off[gw];
  int jend = g_off[gw + 1];
  if (jend < j) jend = j;  // defensive clamp
  float a0A=0.f,a1A=0.f,a2A=0.f,a3A=0.f,a4A=0.f,wA=0.f;
  float a0B=0.f,a1B=0.f,a2B=0.f,a3B=0.f,a4B=0.f,wB=0.f;
#define G2(A0,A1,A2,A3,A4,WW,J) {                                    \
    int s0 = RFL(g_csr[(J)+0]), s1 = RFL(g_csr[(J)+1]);              \
    int s2 = RFL(g_csr[(J)+2]), s3 = RFL(g_csr[(J)+3]);              \
    int ssx = sl2 ? (sl1 ? s3 : s2) : (sl1 ? s1 : s0);               \
    const uint* rowp = &g_h2b[ssx * 48];                             \
    float tt = ((const float*)(rowp + 40))[hh];                      \
    uint2 va = *(const uint2*)&rowp[2 * il];                         \
    uint vb = ((const ushort*)(rowp + 32))[il];                      \
    float e = __expf(lrelu(tt + sdl));                               \
    A0 = fmaf(blo(va.x), e, A0); A1 = fmaf(bhi(va.x), e, A1);        \
    A2 = fmaf(blo(va.y), e, A2); A3 = fmaf(bhi(va.y), e, A3);        \
    A4 = fmaf(__uint_as_float(vb << 16), e, A4);                     \
    WW += e; }
  for (; j + 8 <= jend; j += 8) {
    G2(a0A,a1A,a2A,a3A,a4A,wA,j)
    G2(a0B,a1B,a2B,a3B,a4B,wB,j+4)
  }
  if (j + 4 <= jend) { G2(a0A,a1A,a2A,a3A,a4A,wA,j); j += 4; }
#undef G2
  // robust per-edge tail (<=3 iters): slot 0 accumulates, others add 0
  for (; j < jend; j++) {
    int s0 = RFL(g_csr[j]);
    const uint* rowp = &g_h2b[s0 * 48];
    float tt = ((const float*)(rowp + 40))[hh];
    uint2 va = *(const uint2*)&rowp[2 * il];
    uint vb = ((const ushort*)(rowp + 32))[il];
    float e = (sl == 0) ? __expf(lrelu(tt + sdl)) : 0.f;
    a0B = fmaf(blo(va.x), e, a0B); a1B = fmaf(bhi(va.x), e, a1B);
    a2B = fmaf(blo(va.y), e, a2B); a3B = fmaf(bhi(va.y), e, a3B);
    a4B = fmaf(__uint_as_float(vb << 16), e, a4B);
    wB += e;
  }
  float a0 = a0A + a0B, a1 = a1A + a1B, a2 = a2A + a2B;
  float a3 = a3A + a3B, a4 = a4A + a4B, w = wA + wB;
  a0 += __shfl_xor(a0, 16); a0 += __shfl_xor(a0, 32);
  a1 += __shfl_xor(a1, 16); a1 += __shfl_xor(a1, 32);
  a2 += __shfl_xor(a2, 16); a2 += __shfl_xor(a2, 32);
  a3 += __shfl_xor(a3, 16); a3 += __shfl_xor(a3, 32);
  a4 += __shfl_xor(a4, 16); a4 += __shfl_xor(a4, 32);
  w  += __shfl_xor(w, 16);  w  += __shfl_xor(w, 32);
  float tsl = ((const float*)(g_h2b + (size_t)gw * 48 + 40))[hh];
  float es = __expf(lrelu(tsl + sdl));
  const float* h2row = &g_h2[gw * HC2 + c0];  // self loop fp32
  a0 = fmaf(h2row[0], es, a0); a1 = fmaf(h2row[1], es, a1);
  a2 = fmaf(h2row[2], es, a2); a3 = fmaf(h2row[3], es, a3);
  a4 = fmaf(h2row[4], es, a4);
  w += es;
  float inv = 1.f / w;
  float v0 = a0 * inv + bb0, v1 = a1 * inv + bb1, v2 = a2 * inv + bb2;
  float v3 = a3 * inv + bb3, v4 = a4 * inv + bb4;
  // log_softmax over the 80 chs spread across the 16-lane group
  float mx = fmaxf(fmaxf(fmaxf(v0, v1), fmaxf(v2, v3)), v4);
  for (int o = 1; o < 16; o <<= 1) mx = fmaxf(mx, __shfl_xor(mx, o));
  float sp = __expf(v0 - mx) + __expf(v1 - mx) + __expf(v2 - mx) +
             __expf(v3 - mx) + __expf(v4 - mx);
  for (int o = 1; o < 16; o <<= 1) sp += __shfl_xor(sp, o);
  float lse = mx + __logf(sp);
  if (sl == 0) {
    float* op = &out[gw * HC2 + c0];
    op[0] = v0 - lse; op[1] = v1 - lse; op[2] = v2 - lse;
    op[3] = v3 - lse; op[4] = v4 - lse;
  }
}

// ---------------- launch ----------------
extern "C" void kernel_launch(void* const* d_in, const int* in_sizes, int n_in,
                              void* d_out, int out_size, void* d_ws, size_t ws_size,
                              hipStream_t stream) {
  (void)in_sizes; (void)n_in; (void)out_size; (void)d_ws; (void)ws_size;
  const float* x   = (const float*)d_in[0];
  const int*   ei  = (const int*)d_in[1];
  const float* W1  = (const float*)d_in[2];
  const float* as1 = (const float*)d_in[3];
  const float* ad1 = (const float*)d_in[4];
  const float* b1  = (const float*)d_in[5];
  const float* W2  = (const float*)d_in[6];
  const float* as2 = (const float*)d_in[7];
  const float* ad2 = (const float*)d_in[8];
  const float* b2  = (const float*)d_in[9];
  float* out = (float*)d_out;

  // CSR build (radix partition + src-range ordering; shared by both layers)
  p1count_kernel<<<NBLK, 256, 0, stream>>>(ei);
  scn_block_kernel<<<SCNB, 1024, 0, stream>>>();
  scn_add_kernel<<<SCNB, 1024, 0, stream>>>();
  p1scatter_kernel<<<NBLK, 256, 0, stream>>>(ei);
  p2build_kernel<<<NBUK, 1024, 0, stream>>>();

  // layer 1
  w1cast_kernel<<<64, 256, 0, stream>>>(W1);
  gemm1_kernel<<<1563, 256, 0, stream>>>(x);
  s_kernel<1><<<3125, 256, 0, stream>>>(as1, ad1);
  agg1_kernel<<<25000, 256, 0, stream>>>(b1);

  // layer 2
  gemm2_kernel<<<2048, 256, 0, stream>>>(W2);
  s_kernel<2><<<3125, 256, 0, stream>>>(as2, ad2);
  agg2_kernel<<<25000, 256, 0, stream>>>(out, b2);
}

// Round 8
// 736.192 us; speedup vs baseline: 1.0699x; 1.0571x over previous
//
#include <hip/hip_runtime.h>
#include <math.h>

#define NN 100000
#define NE 3200000
#define FIN 512
#define NH 8
#define C1 8
#define HC1 64
#define C2 10
#define HC2 80

// radix CSR build
#define EPB 4096
#define NBLK 782           // ceil(NE/EPB)
#define NBUK 196           // ceil(NN/512)
#define SCN (NBUK * NBLK)  // 153272
#define SCNB 150           // ceil(SCN/1024)

typedef unsigned int uint;
typedef unsigned short ushort;
using bf16x8 = __attribute__((ext_vector_type(8))) short;
using f32x4  = __attribute__((ext_vector_type(4))) float;

#define RFL(x) __builtin_amdgcn_readfirstlane((int)(x))

// ---------------- static scratch ----------------
__device__ float g_h1[NN * HC1];        // x @ W1 (fp32, MFMA out)
__device__ float g_hact[NN * HC1];      // elu(agg1 + b1)
__device__ float g_h2[NN * HC2];        // hact @ W2 (fp32)
__device__ uint  g_h1b[NN * 32];        // h1 as bf16 pairs (uint k: chs 2k,2k+1), 128B row
__device__ uint  g_h2b[NN * 48];        // layer-2 combined row, 192B aligned:
                                        //   uints 0..31  : bf16 feature pairs (permuted split A)
                                        //   uints 32..39 : 16 ushort bf16 (split B, ch .. +4)
                                        //   uints 40..47 : fp32 ssrc[8 heads]
__device__ uint  g_w1bt[64 * 256];      // W1 transposed bf16 pairs: [n][kp]
__device__ float g_ssrc[NN * NH];       // layer-1 src scores (self-loop only now)
__device__ float g_sdst[NN * NH];
__device__ int   g_off[NN + 1];
__device__ uint  g_pscan[SCN];          // per-(bucket,block) counts -> scanned
__device__ uint  g_bsum2[256];
__device__ uint  g_ebuf[NE];            // packed (dlow<<17)|src, bucket-partitioned
__device__ int   g_csr[NE];

__device__ __forceinline__ float lrelu(float x) { return fmaxf(x, 0.2f * x); }

__device__ __forceinline__ uint bf16_rne(float x) {
  uint u = __float_as_uint(x);
  u += 0x7fffu + ((u >> 16) & 1u);
  return u >> 16;
}
__device__ __forceinline__ uint packbf2(float lo, float hi) {
  return bf16_rne(lo) | (bf16_rne(hi) << 16);
}
__device__ __forceinline__ float blo(uint v) { return __uint_as_float(v << 16); }
__device__ __forceinline__ float bhi(uint v) { return __uint_as_float(v & 0xffff0000u); }

// ---------------- CSR build: radix partition by dst, no global atomics ----------
__global__ __launch_bounds__(256) void p1count_kernel(const int* __restrict__ ei) {
  __shared__ uint cnt[NBUK];
  int tid = threadIdx.x;
  for (int i = tid; i < NBUK; i += 256) cnt[i] = 0;
  __syncthreads();
  const int* dstp = ei + NE;
  int base = blockIdx.x * EPB;
#pragma unroll 4
  for (int k = 0; k < 16; k++) {
    int e = base + k * 256 + tid;
    if (e < NE) atomicAdd(&cnt[dstp[e] >> 9], 1u);
  }
  __syncthreads();
  for (int i = tid; i < NBUK; i += 256) g_pscan[i * NBLK + blockIdx.x] = cnt[i];
}

__global__ __launch_bounds__(1024) void scn_block_kernel() {
  __shared__ uint sd[1024];
  int tid = threadIdx.x;
  int i = blockIdx.x * 1024 + tid;
  uint v = (i < SCN) ? g_pscan[i] : 0;
  sd[tid] = v;
  __syncthreads();
  for (int off = 1; off < 1024; off <<= 1) {
    uint x = (tid >= off) ? sd[tid - off] : 0;
    __syncthreads();
    sd[tid] += x;
    __syncthreads();
  }
  if (i < SCN) g_pscan[i] = sd[tid] - v;  // exclusive within block
  if (tid == 1023) g_bsum2[blockIdx.x] = sd[1023];
}

// scn_add with the top-level scan folded in: each block redundantly scans the
// 150 block sums in LDS (removes the serial 1-block scn_tops launch).
__global__ __launch_bounds__(1024) void scn_add_kernel() {
  __shared__ uint sums[256];
  __shared__ uint ex[256];
  int tid = threadIdx.x;
  uint orig = 0;
  if (tid < 256) {
    orig = (tid < SCNB) ? g_bsum2[tid] : 0;
    sums[tid] = orig;
  }
  __syncthreads();
  for (int off = 1; off < 256; off <<= 1) {
    uint x = 0;
    if (tid < 256 && tid >= off) x = sums[tid - off];
    __syncthreads();
    if (tid < 256) sums[tid] += x;
    __syncthreads();
  }
  if (tid < 256) ex[tid] = sums[tid] - orig;  // exclusive
  __syncthreads();
  uint add = ex[blockIdx.x];
  int i = blockIdx.x * 1024 + tid;
  if (i < SCN) g_pscan[i] += add;
}

__global__ __launch_bounds__(256) void p1scatter_kernel(const int* __restrict__ ei) {
  __shared__ uint cur[NBUK];
  int tid = threadIdx.x;
  for (int i = tid; i < NBUK; i += 256) cur[i] = g_pscan[i * NBLK + blockIdx.x];
  __syncthreads();
  const int* srcp = ei;
  const int* dstp = ei + NE;
  int base = blockIdx.x * EPB;
#pragma unroll 4
  for (int k = 0; k < 16; k++) {
    int e = base + k * 256 + tid;
    if (e < NE) {
      int d = dstp[e], s = srcp[e];
      uint pos = atomicAdd(&cur[d >> 9], 1u);  // LDS atomic
      g_ebuf[pos] = ((uint)(d & 511) << 17) | (uint)s;
    }
  }
}

// Pass 2: per-bucket 4096-bin (dlow x src-range) histogram/scan/scatter.
// Within-node edge lists come out ordered by src>>14 (8 ranges of 16K nodes)
// -> agg kernels sweep src ranges in order => XCD-L2 locality for the gathers.
__global__ __launch_bounds__(1024) void p2build_kernel() {
  __shared__ uint hist[4096];   // reused as cursors in pass 2
  __shared__ uint excl[4096];
  __shared__ uint tsum[1024];
  int tid = threadIdx.x;
  int b = blockIdx.x;
  uint bstart = g_pscan[b * NBLK];
  uint bend = (b < NBUK - 1) ? g_pscan[(b + 1) * NBLK] : NE;
  for (int i = tid; i < 4096; i += 1024) hist[i] = 0;
  __syncthreads();
  for (uint j = bstart + tid; j < bend; j += 1024) {
    uint v = g_ebuf[j];
    uint bin = ((v >> 17) << 3) | ((v & 0x1FFFFu) >> 14);
    atomicAdd(&hist[bin], 1u);
  }
  __syncthreads();
  uint h0 = hist[tid * 4 + 0], h1 = hist[tid * 4 + 1];
  uint h2 = hist[tid * 4 + 2], h3 = hist[tid * 4 + 3];
  uint s1 = h0 + h1, s2 = s1 + h2, s3 = s2 + h3;
  tsum[tid] = s3;
  __syncthreads();
  for (int off = 1; off < 1024; off <<= 1) {
    uint x = (tid >= off) ? tsum[tid - off] : 0;
    __syncthreads();
    tsum[tid] += x;
    __syncthreads();
  }
  uint te = tsum[tid] - s3;  // exclusive over threads
  excl[tid * 4 + 0] = te;
  excl[tid * 4 + 1] = te + h0;
  excl[tid * 4 + 2] = te + s1;
  excl[tid * 4 + 3] = te + s2;
  __syncthreads();
  if (tid < 512) {
    int dst = b * 512 + tid;
    if (dst < NN) g_off[dst] = (int)(bstart + excl[tid * 8]);
  }
  if (b == NBUK - 1 && tid == 0) g_off[NN] = NE;
  for (int i = tid; i < 4096; i += 1024) hist[i] = excl[i];  // cursors
  __syncthreads();
  for (uint j = bstart + tid; j < bend; j += 1024) {
    uint v = g_ebuf[j];
    uint bin = ((v >> 17) << 3) | ((v & 0x1FFFFu) >> 14);
    uint pos = bstart + atomicAdd(&hist[bin], 1u);  // LDS atomic
    g_csr[pos] = (int)(v & 0x1FFFFu);
  }
}

// ---------------- W1 -> bf16 transposed pairs ----------------
__global__ __launch_bounds__(256) void w1cast_kernel(const float* __restrict__ W) {
  int idx = blockIdx.x * 256 + threadIdx.x;  // 0..16383
  int n = idx & 63, kp = idx >> 6;           // kp 0..255
  float lo = W[(2 * kp) * HC1 + n];
  float hi = W[(2 * kp + 1) * HC1 + n];
  g_w1bt[n * 256 + kp] = packbf2(lo, hi);
}

// ---------------- GEMM1: g_h1 = X[NN,512] @ W1[512,64] via bf16 MFMA ------------
__device__ __forceinline__ int sw_idx(int row, int g) {
  return row * 32 + ((g ^ (row & 7)) << 2);
}

__global__ __launch_bounds__(256) void gemm1_kernel(const float* __restrict__ X) {
  __shared__ uint sA[64 * 32];
  __shared__ uint sB[64 * 32];
  int t = threadIdx.x;
  int w = t >> 6, l = t & 63;
  int q = l >> 4, c = l & 15;
  int r0 = blockIdx.x * 64;
  int sr = t >> 2;             // 0..63 (row / n)
  int sc = t & 3;              // quarter
  int xrow = r0 + sr; if (xrow >= NN) xrow = NN - 1;
  const float* xbase = &X[(long)xrow * FIN + sc * 16];
  const uint* wbase = &g_w1bt[sr * 256 + sc * 8];
  f32x4 acc[4] = {{0.f,0.f,0.f,0.f},{0.f,0.f,0.f,0.f},{0.f,0.f,0.f,0.f},{0.f,0.f,0.f,0.f}};
  for (int k0 = 0; k0 < FIN; k0 += 64) {
    __syncthreads();
    float4 f0 = *(const float4*)&xbase[k0 + 0];
    float4 f1 = *(const float4*)&xbase[k0 + 4];
    float4 f2 = *(const float4*)&xbase[k0 + 8];
    float4 f3 = *(const float4*)&xbase[k0 + 12];
    uint4 a0 = make_uint4(packbf2(f0.x, f0.y), packbf2(f0.z, f0.w),
                          packbf2(f1.x, f1.y), packbf2(f1.z, f1.w));
    uint4 a1 = make_uint4(packbf2(f2.x, f2.y), packbf2(f2.z, f2.w),
                          packbf2(f3.x, f3.y), packbf2(f3.z, f3.w));
    *(uint4*)&sA[sw_idx(sr, sc * 2 + 0)] = a0;
    *(uint4*)&sA[sw_idx(sr, sc * 2 + 1)] = a1;
    uint4 b0 = *(const uint4*)&wbase[(k0 >> 1) + 0];
    uint4 b1 = *(const uint4*)&wbase[(k0 >> 1) + 4];
    *(uint4*)&sB[sw_idx(sr, sc * 2 + 0)] = b0;
    *(uint4*)&sB[sw_idx(sr, sc * 2 + 1)] = b1;
    __syncthreads();
#pragma unroll
    for (int ks = 0; ks < 2; ks++) {
      int g = ks * 4 + q;
      bf16x8 a = *(const bf16x8*)&sA[sw_idx(w * 16 + c, g)];
#pragma unroll
      for (int nt = 0; nt < 4; nt++) {
        bf16x8 b = *(const bf16x8*)&sB[sw_idx(nt * 16 + c, g)];
        acc[nt] = __builtin_amdgcn_mfma_f32_16x16x32_bf16(a, b, acc[nt], 0, 0, 0);
      }
    }
  }
  int orow0 = r0 + w * 16 + q * 4;
#pragma unroll
  for (int nt = 0; nt < 4; nt++) {
#pragma unroll
    for (int r = 0; r < 4; r++) {
      int row = orow0 + r;
      if (row < NN) g_h1[row * HC1 + nt * 16 + c] = acc[nt][r];
    }
  }
}

// ---------------- attention scores + bf16 packing ----------------
// Layer 1: g_h1b uint k (0..31) = chs 2k,2k+1 (lane il reads uint2 -> chs 4il..4il+3)
//          edge scores are RECOMPUTED from bf16 features in agg1 (saves a line);
//          fp32 g_ssrc kept for the self loop.
// Layer 2: combined 192B row in g_h2b (48 uints):
//   A (uints 0..31):  uints 2*il, 2*il+1 = chs 10*(il>>1) + 5*(il&1) + {0,1,2,3}
//   B (uints 32..39 as 16 ushorts): ushort il = ch 10*(il>>1) + 5*(il&1) + 4
//   scores (uints 40..47): fp32 ssrc[head]  -> whole row = exactly 3 cachelines
template <int LAYER>
__global__ __launch_bounds__(256) void s_kernel(const float* __restrict__ a_src,
                                                const float* __restrict__ a_dst) {
  constexpr int C = (LAYER == 1) ? C1 : C2;
  const float* Hm = (LAYER == 1) ? g_h1 : g_h2;
  int t = blockIdx.x * 256 + threadIdx.x;
  if (t >= NN * NH) return;
  int h = t & 7;
  const float* row = &Hm[t * C];
  float ss = 0.f, sdd = 0.f;
  float vals[C];
#pragma unroll
  for (int c = 0; c < C; c++) {
    float v = row[c];
    vals[c] = v;
    ss = fmaf(v, a_src[h * C + c], ss);
    sdd = fmaf(v, a_dst[h * C + c], sdd);
  }
  g_sdst[t] = sdd;
  if constexpr (LAYER == 1) {
    g_ssrc[t] = ss;
#pragma unroll
    for (int j = 0; j < 4; j++)
      g_h1b[t * 4 + j] = packbf2(vals[2 * j], vals[2 * j + 1]);
  } else {
    int n = t >> 3;
#pragma unroll
    for (int b = 0; b < 2; b++) {
      int il = 2 * h + b;
      g_h2b[n * 48 + 2 * il + 0] = packbf2(vals[5 * b + 0], vals[5 * b + 1]);
      g_h2b[n * 48 + 2 * il + 1] = packbf2(vals[5 * b + 2], vals[5 * b + 3]);
      ((ushort*)&g_h2b[n * 48 + 32])[il] = (ushort)bf16_rne(vals[5 * b + 4]);
    }
    g_h2b[n * 48 + 40 + h] = __float_as_uint(ss);  // embedded fp32 score
  }
}

// ---- layer-1 aggregation: wave/node, 4 edge-slots x 16 lanes x 4 channels ----
// Edge score recomputed from the gathered bf16 features (head = il>>1 owns
// chs in lanes il, il^1): p = dot4 + shfl_xor(p,1). 2 cachelines/edge total.
__global__ __launch_bounds__(256) void agg1_kernel(const float* __restrict__ b1,
                                                   const float* __restrict__ as1) {
  int gw = RFL((blockIdx.x * 256 + threadIdx.x) >> 6);
  if (gw >= NN) return;
  int lane = threadIdx.x & 63;
  int sl = lane >> 4, il = lane & 15;
  int hh = il >> 1;
  bool sl1 = (sl & 1) != 0, sl2 = (sl & 2) != 0;
  float sdl = g_sdst[gw * NH + hh];
  float4 asv = *(const float4*)&as1[hh * 8 + 4 * (il & 1)];  // a_src coeffs for my 4 chs
  float4 bb = *(const float4*)&b1[4 * il];
  int j = g_off[gw];
  int jend = g_off[gw + 1];
  if (jend < j) jend = j;  // defensive clamp
  float a0A=0.f,a1A=0.f,a2A=0.f,a3A=0.f,wA=0.f;
  float a0B=0.f,a1B=0.f,a2B=0.f,a3B=0.f,wB=0.f;
#define G1(A0,A1,A2,A3,WW,J) {                                       \
    int s0 = RFL(g_csr[(J)+0]), s1 = RFL(g_csr[(J)+1]);              \
    int s2 = RFL(g_csr[(J)+2]), s3 = RFL(g_csr[(J)+3]);              \
    int ssx = sl2 ? (sl1 ? s3 : s2) : (sl1 ? s1 : s0);               \
    uint2 va = *(const uint2*)&g_h1b[ssx * 32 + 2 * il];             \
    float f0 = blo(va.x), f1 = bhi(va.x);                            \
    float f2 = blo(va.y), f3 = bhi(va.y);                            \
    float p = f0 * asv.x;                                            \
    p = fmaf(f1, asv.y, p);                                          \
    p = fmaf(f2, asv.z, p);                                          \
    p = fmaf(f3, asv.w, p);                                          \
    p += __shfl_xor(p, 1);                                           \
    float e = __expf(lrelu(p + sdl));                                \
    A0 = fmaf(f0, e, A0); A1 = fmaf(f1, e, A1);                      \
    A2 = fmaf(f2, e, A2); A3 = fmaf(f3, e, A3);                      \
    WW += e; }
  for (; j + 8 <= jend; j += 8) {
    G1(a0A,a1A,a2A,a3A,wA,j)
    G1(a0B,a1B,a2B,a3B,wB,j+4)
  }
  if (j + 4 <= jend) { G1(a0A,a1A,a2A,a3A,wA,j); j += 4; }
#undef G1
  // robust per-edge tail (<=3 iters): slot 0 accumulates, others add 0
  for (; j < jend; j++) {
    int s0 = RFL(g_csr[j]);
    uint2 va = *(const uint2*)&g_h1b[s0 * 32 + 2 * il];
    float f0 = blo(va.x), f1 = bhi(va.x);
    float f2 = blo(va.y), f3 = bhi(va.y);
    float p = f0 * asv.x;
    p = fmaf(f1, asv.y, p);
    p = fmaf(f2, asv.z, p);
    p = fmaf(f3, asv.w, p);
    p += __shfl_xor(p, 1);
    float e = (sl == 0) ? __expf(lrelu(p + sdl)) : 0.f;
    a0B = fmaf(f0, e, a0B); a1B = fmaf(f1, e, a1B);
    a2B = fmaf(f2, e, a2B); a3B = fmaf(f3, e, a3B);
    wB += e;
  }
  float a0 = a0A + a0B, a1 = a1A + a1B, a2 = a2A + a2B, a3 = a3A + a3B;
  float w = wA + wB;
  a0 += __shfl_xor(a0, 16); a0 += __shfl_xor(a0, 32);
  a1 += __shfl_xor(a1, 16); a1 += __shfl_xor(a1, 32);
  a2 += __shfl_xor(a2, 16); a2 += __shfl_xor(a2, 32);
  a3 += __shfl_xor(a3, 16); a3 += __shfl_xor(a3, 32);
  w  += __shfl_xor(w, 16);  w  += __shfl_xor(w, 32);
  float es = __expf(lrelu(g_ssrc[gw * NH + hh] + sdl));  // self loop: fp32 score
  float4 hv = *(const float4*)&g_h1[gw * HC1 + 4 * il];  // self loop fp32 features
  a0 = fmaf(hv.x, es, a0); a1 = fmaf(hv.y, es, a1);
  a2 = fmaf(hv.z, es, a2); a3 = fmaf(hv.w, es, a3);
  w += es;
  float inv = 1.f / w;
  float v0 = a0 * inv + bb.x, v1 = a1 * inv + bb.y;
  float v2 = a2 * inv + bb.z, v3 = a3 * inv + bb.w;
  v0 = v0 > 0.f ? v0 : __expf(v0) - 1.f;
  v1 = v1 > 0.f ? v1 : __expf(v1) - 1.f;
  v2 = v2 > 0.f ? v2 : __expf(v2) - 1.f;
  v3 = v3 > 0.f ? v3 : __expf(v3) - 1.f;
  if (sl == 0) *(float4*)&g_hact[gw * HC1 + 4 * il] = make_float4(v0, v1, v2, v3);
}

// ---------------- GEMM2: g_h2 = g_hact[NN,64] @ W2[64,80] ----------------
__global__ __launch_bounds__(256) void gemm2_kernel(const float* __restrict__ W) {
  __shared__ float sW[64 * HC2 + 64];
  int tid = threadIdx.x;
  for (int i = tid; i < 64 * HC2; i += 256) sW[i] = W[i];
  for (int i = 64 * HC2 + tid; i < 64 * HC2 + 64; i += 256) sW[i] = 0.f;
  __syncthreads();
  int lane = tid & 63;
  int w0 = (blockIdx.x * 256 + tid) >> 6;
  for (int r = w0; r < NN; r += 8192) {
    float v = g_hact[r * HC1 + lane];
    float acc0 = 0.f, acc1 = 0.f;
#pragma unroll
    for (int k = 0; k < 64; k++) {
      float xk = __shfl(v, k);
      acc0 = fmaf(xk, sW[k * HC2 + lane], acc0);
      acc1 = fmaf(xk, sW[k * HC2 + 64 + lane], acc1);
    }
    g_h2[r * HC2 + lane] = acc0;
    if (lane < 16) g_h2[r * HC2 + 64 + lane] = acc1;
  }
}

// ---- layer-2 aggregation: 4 edge-slots x 16 lanes x 5 channels + log_softmax --
// Combined 192B row (features + embedded fp32 scores) => 3 cachelines/edge.
__global__ __launch_bounds__(256) void agg2_kernel(float* __restrict__ out,
                                                   const float* __restrict__ b2) {
  int gw = RFL((blockIdx.x * 256 + threadIdx.x) >> 6);
  if (gw >= NN) return;
  int lane = threadIdx.x & 63;
  int sl = lane >> 4, il = lane & 15;
  int hh = il >> 1, bq = il & 1;
  int c0 = 10 * hh + 5 * bq;  // first true channel of this lane
  bool sl1 = (sl & 1) != 0, sl2 = (sl & 2) != 0;
  float sdl = g_sdst[gw * NH + hh];
  float bb0 = b2[c0 + 0], bb1 = b2[c0 + 1], bb2 = b2[c0 + 2];
  float bb3 = b2[c0 + 3], bb4 = b2[c0 + 4];
  int j = g_off[gw];
  int jend = g_off[gw + 1];
  if (jend < j) jend = j;  // defensive clamp
  float a0A=0.f,a1A=0.f,a2A=0.f,a3A=0.f,a4A=0.f,wA=0.f;
  float a0B=0.f,a1B=0.f,a2B=0.f,a3B=0.f,a4B=0.f,wB=0.f;
#define G2(A0,A1,A2,A3,A4,WW,J) {                                    \
    int s0 = RFL(g_csr[(J)+0]), s1 = RFL(g_csr[(J)+1]);              \
    int s2 = RFL(g_csr[(J)+2]), s3 = RFL(g_csr[(J)+3]);              \
    int ssx = sl2 ? (sl1 ? s3 : s2) : (sl1 ? s1 : s0);               \
    const uint* rowp = &g_h2b[ssx * 48];                             \
    float tt = ((const float*)(rowp + 40))[hh];                      \
    uint2 va = *(const uint2*)&rowp[2 * il];                         \
    uint vb = ((const ushort*)(rowp + 32))[il];                      \
    float e = __expf(lrelu(tt + sdl));                               \
    A0 = fmaf(blo(va.x), e, A0); A1 = fmaf(bhi(va.x), e, A1);        \
    A2 = fmaf(blo(va.y), e, A2); A3 = fmaf(bhi(va.y), e, A3);        \
    A4 = fmaf(__uint_as_float(vb << 16), e, A4);                     \
    WW += e; }
  for (; j + 8 <= jend; j += 8) {
    G2(a0A,a1A,a2A,a3A,a4A,wA,j)
    G2(a0B,a1B,a2B,a3B,a4B,wB,j+4)
  }
  if (j + 4 <= jend) { G2(a0A,a1A,a2A,a3A,a4A,wA,j); j += 4; }
#undef G2
  // robust per-edge tail (<=3 iters): slot 0 accumulates, others add 0
  for (; j < jend; j++) {
    int s0 = RFL(g_csr[j]);
    const uint* rowp = &g_h2b[s0 * 48];
    float tt = ((const float*)(rowp + 40))[hh];
    uint2 va = *(const uint2*)&rowp[2 * il];
    uint vb = ((const ushort*)(rowp + 32))[il];
    float e = (sl == 0) ? __expf(lrelu(tt + sdl)) : 0.f;
    a0B = fmaf(blo(va.x), e, a0B); a1B = fmaf(bhi(va.x), e, a1B);
    a2B = fmaf(blo(va.y), e, a2B); a3B = fmaf(bhi(va.y), e, a3B);
    a4B = fmaf(__uint_as_float(vb << 16), e, a4B);
    wB += e;
  }
  float a0 = a0A + a0B, a1 = a1A + a1B, a2 = a2A + a2B;
  float a3 = a3A + a3B, a4 = a4A + a4B, w = wA + wB;
  a0 += __shfl_xor(a0, 16); a0 += __shfl_xor(a0, 32);
  a1 += __shfl_xor(a1, 16); a1 += __shfl_xor(a1, 32);
  a2 += __shfl_xor(a2, 16); a2 += __shfl_xor(a2, 32);
  a3 += __shfl_xor(a3, 16); a3 += __shfl_xor(a3, 32);
  a4 += __shfl_xor(a4, 16); a4 += __shfl_xor(a4, 32);
  w  += __shfl_xor(w, 16);  w  += __shfl_xor(w, 32);
  float tsl = ((const float*)(g_h2b + (size_t)gw * 48 + 40))[hh];
  float es = __expf(lrelu(tsl + sdl));
  const float* h2row = &g_h2[gw * HC2 + c0];  // self loop fp32
  a0 = fmaf(h2row[0], es, a0); a1 = fmaf(h2row[1], es, a1);
  a2 = fmaf(h2row[2], es, a2); a3 = fmaf(h2row[3], es, a3);
  a4 = fmaf(h2row[4], es, a4);
  w += es;
  float inv = 1.f / w;
  float v0 = a0 * inv + bb0, v1 = a1 * inv + bb1, v2 = a2 * inv + bb2;
  float v3 = a3 * inv + bb3, v4 = a4 * inv + bb4;
  // log_softmax over the 80 chs spread across the 16-lane group
  float mx = fmaxf(fmaxf(fmaxf(v0, v1), fmaxf(v2, v3)), v4);
  for (int o = 1; o < 16; o <<= 1) mx = fmaxf(mx, __shfl_xor(mx, o));
  float sp = __expf(v0 - mx) + __expf(v1 - mx) + __expf(v2 - mx) +
             __expf(v3 - mx) + __expf(v4 - mx);
  for (int o = 1; o < 16; o <<= 1) sp += __shfl_xor(sp, o);
  float lse = mx + __logf(sp);
  if (sl == 0) {
    float* op = &out[gw * HC2 + c0];
    op[0] = v0 - lse; op[1] = v1 - lse; op[2] = v2 - lse;
    op[3] = v3 - lse; op[4] = v4 - lse;
  }
}

// ---------------- launch ----------------
extern "C" void kernel_launch(void* const* d_in, const int* in_sizes, int n_in,
                              void* d_out, int out_size, void* d_ws, size_t ws_size,
                              hipStream_t stream) {
  (void)in_sizes; (void)n_in; (void)out_size; (void)d_ws; (void)ws_size;
  const float* x   = (const float*)d_in[0];
  const int*   ei  = (const int*)d_in[1];
  const float* W1  = (const float*)d_in[2];
  const float* as1 = (const float*)d_in[3];
  const float* ad1 = (const float*)d_in[4];
  const float* b1  = (const float*)d_in[5];
  const float* W2  = (const float*)d_in[6];
  const float* as2 = (const float*)d_in[7];
  const float* ad2 = (const float*)d_in[8];
  const float* b2  = (const float*)d_in[9];
  float* out = (float*)d_out;

  // CSR build (radix partition + src-range ordering; shared by both layers)
  p1count_kernel<<<NBLK, 256, 0, stream>>>(ei);
  scn_block_kernel<<<SCNB, 1024, 0, stream>>>();
  scn_add_kernel<<<SCNB, 1024, 0, stream>>>();
  p1scatter_kernel<<<NBLK, 256, 0, stream>>>(ei);
  p2build_kernel<<<NBUK, 1024, 0, stream>>>();

  // layer 1
  w1cast_kernel<<<64, 256, 0, stream>>>(W1);
  gemm1_kernel<<<1563, 256, 0, stream>>>(x);
  s_kernel<1><<<3125, 256, 0, stream>>>(as1, ad1);
  agg1_kernel<<<25000, 256, 0, stream>>>(b1, as1);

  // layer 2
  gemm2_kernel<<<2048, 256, 0, stream>>>(W2);
  s_kernel<2><<<3125, 256, 0, stream>>>(as2, ad2);
  agg2_kernel<<<25000, 256, 0, stream>>>(out, b2);
}

// Round 9
// 728.463 us; speedup vs baseline: 1.0813x; 1.0106x over previous
//
#include <hip/hip_runtime.h>
#include <math.h>

#define NN 100000
#define NE 3200000
#define FIN 512
#define NH 8
#define C1 8
#define HC1 64
#define C2 10
#define HC2 80

// radix CSR build
#define EPB 4096
#define NBLK 782           // ceil(NE/EPB)
#define NBUK 196           // ceil(NN/512)
#define SCN (NBUK * NBLK)  // 153272
#define SCNB 150           // ceil(SCN/1024)

typedef unsigned int uint;
typedef unsigned short ushort;
using bf16x8 = __attribute__((ext_vector_type(8))) short;
using f32x4  = __attribute__((ext_vector_type(4))) float;

#define RFL(x) __builtin_amdgcn_readfirstlane((int)(x))

// ---------------- static scratch ----------------
__device__ float g_h1[NN * HC1];        // x @ W1 (fp32)
__device__ float g_hact[NN * HC1];      // elu(agg1 + b1)
__device__ float g_h2[NN * HC2];        // hact @ W2 (fp32)
__device__ uint  g_h1b[NN * 32];        // h1 as bf16 pairs (uint k: chs 2k,2k+1), 128B row
__device__ uint  g_h2b[NN * 48];        // layer-2 combined row, 192B aligned:
                                        //   uints 0..31  : bf16 feature pairs (permuted split A)
                                        //   uints 32..39 : 16 ushort bf16 (split B, ch .. +4)
                                        //   uints 40..47 : fp32 ssrc[8 heads]
__device__ uint  g_w1bt[64 * 256];      // W1 transposed bf16 pairs: [n][kp]
__device__ float g_ssrc[NN * NH];       // layer-1 src scores (self-loop only)
__device__ float g_sdst[NN * NH];
__device__ int   g_off[NN + 1];
__device__ uint  g_pscan[SCN];          // per-(bucket,block) counts -> scanned
__device__ uint  g_bsum2[256];
__device__ uint  g_ebuf[NE];            // packed (dlow<<17)|src, bucket-partitioned
__device__ int   g_csr[NE];

__device__ __forceinline__ float lrelu(float x) { return fmaxf(x, 0.2f * x); }

__device__ __forceinline__ uint bf16_rne(float x) {
  uint u = __float_as_uint(x);
  u += 0x7fffu + ((u >> 16) & 1u);
  return u >> 16;
}
__device__ __forceinline__ uint packbf2(float lo, float hi) {
  return bf16_rne(lo) | (bf16_rne(hi) << 16);
}
__device__ __forceinline__ float blo(uint v) { return __uint_as_float(v << 16); }
__device__ __forceinline__ float bhi(uint v) { return __uint_as_float(v & 0xffff0000u); }

// ---------------- CSR build: radix partition by dst, no global atomics ----------
__global__ __launch_bounds__(256) void p1count_kernel(const int* __restrict__ ei) {
  __shared__ uint cnt[NBUK];
  int tid = threadIdx.x;
  for (int i = tid; i < NBUK; i += 256) cnt[i] = 0;
  __syncthreads();
  const int* dstp = ei + NE;
  int base = blockIdx.x * EPB;
#pragma unroll 4
  for (int k = 0; k < 16; k++) {
    int e = base + k * 256 + tid;
    if (e < NE) atomicAdd(&cnt[dstp[e] >> 9], 1u);
  }
  __syncthreads();
  for (int i = tid; i < NBUK; i += 256) g_pscan[i * NBLK + blockIdx.x] = cnt[i];
}

__global__ __launch_bounds__(1024) void scn_block_kernel() {
  __shared__ uint sd[1024];
  int tid = threadIdx.x;
  int i = blockIdx.x * 1024 + tid;
  uint v = (i < SCN) ? g_pscan[i] : 0;
  sd[tid] = v;
  __syncthreads();
  for (int off = 1; off < 1024; off <<= 1) {
    uint x = (tid >= off) ? sd[tid - off] : 0;
    __syncthreads();
    sd[tid] += x;
    __syncthreads();
  }
  if (i < SCN) g_pscan[i] = sd[tid] - v;  // exclusive within block
  if (tid == 1023) g_bsum2[blockIdx.x] = sd[1023];
}

// scn_add with the top-level scan folded in: each block redundantly scans the
// 150 block sums in LDS (removes the serial 1-block scn_tops launch).
__global__ __launch_bounds__(1024) void scn_add_kernel() {
  __shared__ uint sums[256];
  __shared__ uint ex[256];
  int tid = threadIdx.x;
  uint orig = 0;
  if (tid < 256) {
    orig = (tid < SCNB) ? g_bsum2[tid] : 0;
    sums[tid] = orig;
  }
  __syncthreads();
  for (int off = 1; off < 256; off <<= 1) {
    uint x = 0;
    if (tid < 256 && tid >= off) x = sums[tid - off];
    __syncthreads();
    if (tid < 256) sums[tid] += x;
    __syncthreads();
  }
  if (tid < 256) ex[tid] = sums[tid] - orig;  // exclusive
  __syncthreads();
  uint add = ex[blockIdx.x];
  int i = blockIdx.x * 1024 + tid;
  if (i < SCN) g_pscan[i] += add;
}

__global__ __launch_bounds__(256) void p1scatter_kernel(const int* __restrict__ ei) {
  __shared__ uint cur[NBUK];
  int tid = threadIdx.x;
  for (int i = tid; i < NBUK; i += 256) cur[i] = g_pscan[i * NBLK + blockIdx.x];
  __syncthreads();
  const int* srcp = ei;
  const int* dstp = ei + NE;
  int base = blockIdx.x * EPB;
#pragma unroll 4
  for (int k = 0; k < 16; k++) {
    int e = base + k * 256 + tid;
    if (e < NE) {
      int d = dstp[e], s = srcp[e];
      uint pos = atomicAdd(&cur[d >> 9], 1u);  // LDS atomic
      g_ebuf[pos] = ((uint)(d & 511) << 17) | (uint)s;
    }
  }
}

// Pass 2: per-bucket 4096-bin (dlow x src-range) histogram/scan/scatter.
// Within-node edge lists come out ordered by src>>14 (8 ranges of 16K nodes)
// -> agg kernels sweep src ranges in order => XCD-L2 locality for the gathers.
__global__ __launch_bounds__(1024) void p2build_kernel() {
  __shared__ uint hist[4096];   // reused as cursors in pass 2
  __shared__ uint excl[4096];
  __shared__ uint tsum[1024];
  int tid = threadIdx.x;
  int b = blockIdx.x;
  uint bstart = g_pscan[b * NBLK];
  uint bend = (b < NBUK - 1) ? g_pscan[(b + 1) * NBLK] : NE;
  for (int i = tid; i < 4096; i += 1024) hist[i] = 0;
  __syncthreads();
  for (uint j = bstart + tid; j < bend; j += 1024) {
    uint v = g_ebuf[j];
    uint bin = ((v >> 17) << 3) | ((v & 0x1FFFFu) >> 14);
    atomicAdd(&hist[bin], 1u);
  }
  __syncthreads();
  uint h0 = hist[tid * 4 + 0], h1 = hist[tid * 4 + 1];
  uint h2 = hist[tid * 4 + 2], h3 = hist[tid * 4 + 3];
  uint s1 = h0 + h1, s2 = s1 + h2, s3 = s2 + h3;
  tsum[tid] = s3;
  __syncthreads();
  for (int off = 1; off < 1024; off <<= 1) {
    uint x = (tid >= off) ? tsum[tid - off] : 0;
    __syncthreads();
    tsum[tid] += x;
    __syncthreads();
  }
  uint te = tsum[tid] - s3;  // exclusive over threads
  excl[tid * 4 + 0] = te;
  excl[tid * 4 + 1] = te + h0;
  excl[tid * 4 + 2] = te + s1;
  excl[tid * 4 + 3] = te + s2;
  __syncthreads();
  if (tid < 512) {
    int dst = b * 512 + tid;
    if (dst < NN) g_off[dst] = (int)(bstart + excl[tid * 8]);
  }
  if (b == NBUK - 1 && tid == 0) g_off[NN] = NE;
  for (int i = tid; i < 4096; i += 1024) hist[i] = excl[i];  // cursors
  __syncthreads();
  for (uint j = bstart + tid; j < bend; j += 1024) {
    uint v = g_ebuf[j];
    uint bin = ((v >> 17) << 3) | ((v & 0x1FFFFu) >> 14);
    uint pos = bstart + atomicAdd(&hist[bin], 1u);  // LDS atomic
    g_csr[pos] = (int)(v & 0x1FFFFu);
  }
}

// ---------------- W1 -> bf16 transposed pairs ----------------
__global__ __launch_bounds__(256) void w1cast_kernel(const float* __restrict__ W) {
  int idx = blockIdx.x * 256 + threadIdx.x;  // 0..16383
  int n = idx & 63, kp = idx >> 6;           // kp 0..255
  float lo = W[(2 * kp) * HC1 + n];
  float hi = W[(2 * kp + 1) * HC1 + n];
  g_w1bt[n * 256 + kp] = packbf2(lo, hi);
}

// ---- GEMM1 + fused layer-1 score/pack epilogue (replaces s_kernel<1>) --------
__device__ __forceinline__ int sw_idx(int row, int g) {
  return row * 32 + ((g ^ (row & 7)) << 2);
}

__global__ __launch_bounds__(256) void gemm1_kernel(const float* __restrict__ X,
                                                    const float* __restrict__ as1,
                                                    const float* __restrict__ ad1) {
  __shared__ uint sA[64 * 32];
  __shared__ uint sB[64 * 32];
  __shared__ float sC[64 * 65];   // stride 65: phase-2 reads <=2-way conflicted
  __shared__ float sAs[64], sAd[64];
  int t = threadIdx.x;
  if (t < 64) sAs[t] = as1[t];
  else if (t < 128) sAd[t - 64] = ad1[t - 64];
  int w = t >> 6, l = t & 63;
  int q = l >> 4, c = l & 15;
  int r0 = blockIdx.x * 64;
  int sr = t >> 2;             // 0..63 (row / n)
  int sc = t & 3;              // quarter
  int xrow = r0 + sr; if (xrow >= NN) xrow = NN - 1;
  const float* xbase = &X[(long)xrow * FIN + sc * 16];
  const uint* wbase = &g_w1bt[sr * 256 + sc * 8];
  f32x4 acc[4] = {{0.f,0.f,0.f,0.f},{0.f,0.f,0.f,0.f},{0.f,0.f,0.f,0.f},{0.f,0.f,0.f,0.f}};
  for (int k0 = 0; k0 < FIN; k0 += 64) {
    __syncthreads();
    float4 f0 = *(const float4*)&xbase[k0 + 0];
    float4 f1 = *(const float4*)&xbase[k0 + 4];
    float4 f2 = *(const float4*)&xbase[k0 + 8];
    float4 f3 = *(const float4*)&xbase[k0 + 12];
    uint4 a0 = make_uint4(packbf2(f0.x, f0.y), packbf2(f0.z, f0.w),
                          packbf2(f1.x, f1.y), packbf2(f1.z, f1.w));
    uint4 a1 = make_uint4(packbf2(f2.x, f2.y), packbf2(f2.z, f2.w),
                          packbf2(f3.x, f3.y), packbf2(f3.z, f3.w));
    *(uint4*)&sA[sw_idx(sr, sc * 2 + 0)] = a0;
    *(uint4*)&sA[sw_idx(sr, sc * 2 + 1)] = a1;
    uint4 b0 = *(const uint4*)&wbase[(k0 >> 1) + 0];
    uint4 b1 = *(const uint4*)&wbase[(k0 >> 1) + 4];
    *(uint4*)&sB[sw_idx(sr, sc * 2 + 0)] = b0;
    *(uint4*)&sB[sw_idx(sr, sc * 2 + 1)] = b1;
    __syncthreads();
#pragma unroll
    for (int ks = 0; ks < 2; ks++) {
      int g = ks * 4 + q;
      bf16x8 a = *(const bf16x8*)&sA[sw_idx(w * 16 + c, g)];
#pragma unroll
      for (int nt = 0; nt < 4; nt++) {
        bf16x8 b = *(const bf16x8*)&sB[sw_idx(nt * 16 + c, g)];
        acc[nt] = __builtin_amdgcn_mfma_f32_16x16x32_bf16(a, b, acc[nt], 0, 0, 0);
      }
    }
  }
  // stage C tile to LDS
  int rl0 = w * 16 + q * 4;
#pragma unroll
  for (int nt = 0; nt < 4; nt++)
#pragma unroll
    for (int r = 0; r < 4; r++)
      sC[(rl0 + r) * 65 + nt * 16 + c] = acc[nt][r];
  __syncthreads();
  // phase 2: 512 (row,head) units -> scores + bf16 pack + fp32 h1
#pragma unroll
  for (int k = 0; k < 2; k++) {
    int u = t + 256 * k;
    int rl = u >> 3, h = u & 7;
    int rg = r0 + rl;
    if (rg < NN) {
      float v0 = sC[rl * 65 + 8 * h + 0], v1 = sC[rl * 65 + 8 * h + 1];
      float v2 = sC[rl * 65 + 8 * h + 2], v3 = sC[rl * 65 + 8 * h + 3];
      float v4 = sC[rl * 65 + 8 * h + 4], v5 = sC[rl * 65 + 8 * h + 5];
      float v6 = sC[rl * 65 + 8 * h + 6], v7 = sC[rl * 65 + 8 * h + 7];
      float ss = 0.f, sdd = 0.f;
      ss = fmaf(v0, sAs[8 * h + 0], ss); sdd = fmaf(v0, sAd[8 * h + 0], sdd);
      ss = fmaf(v1, sAs[8 * h + 1], ss); sdd = fmaf(v1, sAd[8 * h + 1], sdd);
      ss = fmaf(v2, sAs[8 * h + 2], ss); sdd = fmaf(v2, sAd[8 * h + 2], sdd);
      ss = fmaf(v3, sAs[8 * h + 3], ss); sdd = fmaf(v3, sAd[8 * h + 3], sdd);
      ss = fmaf(v4, sAs[8 * h + 4], ss); sdd = fmaf(v4, sAd[8 * h + 4], sdd);
      ss = fmaf(v5, sAs[8 * h + 5], ss); sdd = fmaf(v5, sAd[8 * h + 5], sdd);
      ss = fmaf(v6, sAs[8 * h + 6], ss); sdd = fmaf(v6, sAd[8 * h + 6], sdd);
      ss = fmaf(v7, sAs[8 * h + 7], ss); sdd = fmaf(v7, sAd[8 * h + 7], sdd);
      g_ssrc[rg * NH + h] = ss;
      g_sdst[rg * NH + h] = sdd;
      uint4 pk = make_uint4(packbf2(v0, v1), packbf2(v2, v3),
                            packbf2(v4, v5), packbf2(v6, v7));
      *(uint4*)&g_h1b[(rg * 8 + h) * 4] = pk;
      *(float4*)&g_h1[rg * HC1 + 8 * h + 0] = make_float4(v0, v1, v2, v3);
      *(float4*)&g_h1[rg * HC1 + 8 * h + 4] = make_float4(v4, v5, v6, v7);
    }
  }
}

// ---- layer-1 aggregation: wave/node, 4 edge-slots x 16 lanes x 4 channels ----
// Edge score recomputed from the gathered bf16 features (head = il>>1 owns
// chs in lanes il, il^1): p = dot4 + shfl_xor(p,1). 2 cachelines/edge total.
__global__ __launch_bounds__(256) void agg1_kernel(const float* __restrict__ b1,
                                                   const float* __restrict__ as1) {
  int gw = RFL((blockIdx.x * 256 + threadIdx.x) >> 6);
  if (gw >= NN) return;
  int lane = threadIdx.x & 63;
  int sl = lane >> 4, il = lane & 15;
  int hh = il >> 1;
  bool sl1 = (sl & 1) != 0, sl2 = (sl & 2) != 0;
  float sdl = g_sdst[gw * NH + hh];
  float4 asv = *(const float4*)&as1[hh * 8 + 4 * (il & 1)];  // a_src coeffs for my 4 chs
  float4 bb = *(const float4*)&b1[4 * il];
  int j = g_off[gw];
  int jend = g_off[gw + 1];
  if (jend < j) jend = j;  // defensive clamp
  float a0A=0.f,a1A=0.f,a2A=0.f,a3A=0.f,wA=0.f;
  float a0B=0.f,a1B=0.f,a2B=0.f,a3B=0.f,wB=0.f;
#define G1(A0,A1,A2,A3,WW,J) {                                       \
    int s0 = RFL(g_csr[(J)+0]), s1 = RFL(g_csr[(J)+1]);              \
    int s2 = RFL(g_csr[(J)+2]), s3 = RFL(g_csr[(J)+3]);              \
    int ssx = sl2 ? (sl1 ? s3 : s2) : (sl1 ? s1 : s0);               \
    uint2 va = *(const uint2*)&g_h1b[ssx * 32 + 2 * il];             \
    float f0 = blo(va.x), f1 = bhi(va.x);                            \
    float f2 = blo(va.y), f3 = bhi(va.y);                            \
    float p = f0 * asv.x;                                            \
    p = fmaf(f1, asv.y, p);                                          \
    p = fmaf(f2, asv.z, p);                                          \
    p = fmaf(f3, asv.w, p);                                          \
    p += __shfl_xor(p, 1);                                           \
    float e = __expf(lrelu(p + sdl));                                \
    A0 = fmaf(f0, e, A0); A1 = fmaf(f1, e, A1);                      \
    A2 = fmaf(f2, e, A2); A3 = fmaf(f3, e, A3);                      \
    WW += e; }
  for (; j + 8 <= jend; j += 8) {
    G1(a0A,a1A,a2A,a3A,wA,j)
    G1(a0B,a1B,a2B,a3B,wB,j+4)
  }
  if (j + 4 <= jend) { G1(a0A,a1A,a2A,a3A,wA,j); j += 4; }
#undef G1
  // robust per-edge tail (<=3 iters): slot 0 accumulates, others add 0
  for (; j < jend; j++) {
    int s0 = RFL(g_csr[j]);
    uint2 va = *(const uint2*)&g_h1b[s0 * 32 + 2 * il];
    float f0 = blo(va.x), f1 = bhi(va.x);
    float f2 = blo(va.y), f3 = bhi(va.y);
    float p = f0 * asv.x;
    p = fmaf(f1, asv.y, p);
    p = fmaf(f2, asv.z, p);
    p = fmaf(f3, asv.w, p);
    p += __shfl_xor(p, 1);
    float e = (sl == 0) ? __expf(lrelu(p + sdl)) : 0.f;
    a0B = fmaf(f0, e, a0B); a1B = fmaf(f1, e, a1B);
    a2B = fmaf(f2, e, a2B); a3B = fmaf(f3, e, a3B);
    wB += e;
  }
  float a0 = a0A + a0B, a1 = a1A + a1B, a2 = a2A + a2B, a3 = a3A + a3B;
  float w = wA + wB;
  a0 += __shfl_xor(a0, 16); a0 += __shfl_xor(a0, 32);
  a1 += __shfl_xor(a1, 16); a1 += __shfl_xor(a1, 32);
  a2 += __shfl_xor(a2, 16); a2 += __shfl_xor(a2, 32);
  a3 += __shfl_xor(a3, 16); a3 += __shfl_xor(a3, 32);
  w  += __shfl_xor(w, 16);  w  += __shfl_xor(w, 32);
  float es = __expf(lrelu(g_ssrc[gw * NH + hh] + sdl));  // self loop: fp32 score
  float4 hv = *(const float4*)&g_h1[gw * HC1 + 4 * il];  // self loop fp32 features
  a0 = fmaf(hv.x, es, a0); a1 = fmaf(hv.y, es, a1);
  a2 = fmaf(hv.z, es, a2); a3 = fmaf(hv.w, es, a3);
  w += es;
  float inv = 1.f / w;
  float v0 = a0 * inv + bb.x, v1 = a1 * inv + bb.y;
  float v2 = a2 * inv + bb.z, v3 = a3 * inv + bb.w;
  v0 = v0 > 0.f ? v0 : __expf(v0) - 1.f;
  v1 = v1 > 0.f ? v1 : __expf(v1) - 1.f;
  v2 = v2 > 0.f ? v2 : __expf(v2) - 1.f;
  v3 = v3 > 0.f ? v3 : __expf(v3) - 1.f;
  if (sl == 0) *(float4*)&g_hact[gw * HC1 + 4 * il] = make_float4(v0, v1, v2, v3);
}

// ---- GEMM2 + fused layer-2 score/pack epilogue (replaces s_kernel<2>) --------
// Wave writes its 80-ch row to per-wave LDS; lanes 0..7 each own a head:
// dot a_src/a_dst, emit permuted-split g_h2b row + embedded fp32 score + sdst.
__global__ __launch_bounds__(256) void gemm2_kernel(const float* __restrict__ W,
                                                    const float* __restrict__ as2,
                                                    const float* __restrict__ ad2) {
  __shared__ float sW[64 * HC2 + 64];
  __shared__ float sAs[80], sAd[80];
  __shared__ float sH[4][80];
  int tid = threadIdx.x;
  if (tid < 80) sAs[tid] = as2[tid];
  else if (tid < 160) sAd[tid - 80] = ad2[tid - 80];
  for (int i = tid; i < 64 * HC2; i += 256) sW[i] = W[i];
  for (int i = 64 * HC2 + tid; i < 64 * HC2 + 64; i += 256) sW[i] = 0.f;
  __syncthreads();
  int lane = tid & 63;
  int w = tid >> 6;
  int w0 = (blockIdx.x * 256 + tid) >> 6;
  for (int r = w0; r < NN; r += 8192) {
    float v = g_hact[r * HC1 + lane];
    float acc0 = 0.f, acc1 = 0.f;
#pragma unroll
    for (int k = 0; k < 64; k++) {
      float xk = __shfl(v, k);
      acc0 = fmaf(xk, sW[k * HC2 + lane], acc0);
      acc1 = fmaf(xk, sW[k * HC2 + 64 + lane], acc1);
    }
    g_h2[r * HC2 + lane] = acc0;
    if (lane < 16) g_h2[r * HC2 + 64 + lane] = acc1;
    // wave-local epilogue (no barrier needed: same-wave LDS ordering)
    sH[w][lane] = acc0;
    if (lane < 16) sH[w][64 + lane] = acc1;
    if (lane < 8) {
      int h = lane;
      float vv[10];
#pragma unroll
      for (int jj = 0; jj < 10; jj++) vv[jj] = sH[w][10 * h + jj];
      float ss = 0.f, sdd = 0.f;
#pragma unroll
      for (int jj = 0; jj < 10; jj++) {
        ss = fmaf(vv[jj], sAs[10 * h + jj], ss);
        sdd = fmaf(vv[jj], sAd[10 * h + jj], sdd);
      }
      g_sdst[r * NH + h] = sdd;
#pragma unroll
      for (int b = 0; b < 2; b++) {
        int il = 2 * h + b;
        g_h2b[r * 48 + 2 * il + 0] = packbf2(vv[5 * b + 0], vv[5 * b + 1]);
        g_h2b[r * 48 + 2 * il + 1] = packbf2(vv[5 * b + 2], vv[5 * b + 3]);
        ((ushort*)&g_h2b[r * 48 + 32])[il] = (ushort)bf16_rne(vv[5 * b + 4]);
      }
      g_h2b[r * 48 + 40 + h] = __float_as_uint(ss);  // embedded fp32 score
    }
  }
}

// ---- layer-2 aggregation: 4 edge-slots x 16 lanes x 5 channels + log_softmax --
// Combined 192B row (features + embedded fp32 scores) => 3 cachelines/edge.
__global__ __launch_bounds__(256) void agg2_kernel(float* __restrict__ out,
                                                   const float* __restrict__ b2) {
  int gw = RFL((blockIdx.x * 256 + threadIdx.x) >> 6);
  if (gw >= NN) return;
  int lane = threadIdx.x & 63;
  int sl = lane >> 4, il = lane & 15;
  int hh = il >> 1, bq = il & 1;
  int c0 = 10 * hh + 5 * bq;  // first true channel of this lane
  bool sl1 = (sl & 1) != 0, sl2 = (sl & 2) != 0;
  float sdl = g_sdst[gw * NH + hh];
  float bb0 = b2[c0 + 0], bb1 = b2[c0 + 1], bb2 = b2[c0 + 2];
  float bb3 = b2[c0 + 3], bb4 = b2[c0 + 4];
  int j = g_off[gw];
  int jend = g_off[gw + 1];
  if (jend < j) jend = j;  // defensive clamp
  float a0A=0.f,a1A=0.f,a2A=0.f,a3A=0.f,a4A=0.f,wA=0.f;
  float a0B=0.f,a1B=0.f,a2B=0.f,a3B=0.f,a4B=0.f,wB=0.f;
#define G2(A0,A1,A2,A3,A4,WW,J) {                                    \
    int s0 = RFL(g_csr[(J)+0]), s1 = RFL(g_csr[(J)+1]);              \
    int s2 = RFL(g_csr[(J)+2]), s3 = RFL(g_csr[(J)+3]);              \
    int ssx = sl2 ? (sl1 ? s3 : s2) : (sl1 ? s1 : s0);               \
    const uint* rowp = &g_h2b[ssx * 48];                             \
    float tt = ((const float*)(rowp + 40))[hh];                      \
    uint2 va = *(const uint2*)&rowp[2 * il];                         \
    uint vb = ((const ushort*)(rowp + 32))[il];                      \
    float e = __expf(lrelu(tt + sdl));                               \
    A0 = fmaf(blo(va.x), e, A0); A1 = fmaf(bhi(va.x), e, A1);        \
    A2 = fmaf(blo(va.y), e, A2); A3 = fmaf(bhi(va.y), e, A3);        \
    A4 = fmaf(__uint_as_float(vb << 16), e, A4);                     \
    WW += e; }
  for (; j + 8 <= jend; j += 8) {
    G2(a0A,a1A,a2A,a3A,a4A,wA,j)
    G2(a0B,a1B,a2B,a3B,a4B,wB,j+4)
  }
  if (j + 4 <= jend) { G2(a0A,a1A,a2A,a3A,a4A,wA,j); j += 4; }
#undef G2
  // robust per-edge tail (<=3 iters): slot 0 accumulates, others add 0
  for (; j < jend; j++) {
    int s0 = RFL(g_csr[j]);
    const uint* rowp = &g_h2b[s0 * 48];
    float tt = ((const float*)(rowp + 40))[hh];
    uint2 va = *(const uint2*)&rowp[2 * il];
    uint vb = ((const ushort*)(rowp + 32))[il];
    float e = (sl == 0) ? __expf(lrelu(tt + sdl)) : 0.f;
    a0B = fmaf(blo(va.x), e, a0B); a1B = fmaf(bhi(va.x), e, a1B);
    a2B = fmaf(blo(va.y), e, a2B); a3B = fmaf(bhi(va.y), e, a3B);
    a4B = fmaf(__uint_as_float(vb << 16), e, a4B);
    wB += e;
  }
  float a0 = a0A + a0B, a1 = a1A + a1B, a2 = a2A + a2B;
  float a3 = a3A + a3B, a4 = a4A + a4B, w = wA + wB;
  a0 += __shfl_xor(a0, 16); a0 += __shfl_xor(a0, 32);
  a1 += __shfl_xor(a1, 16); a1 += __shfl_xor(a1, 32);
  a2 += __shfl_xor(a2, 16); a2 += __shfl_xor(a2, 32);
  a3 += __shfl_xor(a3, 16); a3 += __shfl_xor(a3, 32);
  a4 += __shfl_xor(a4, 16); a4 += __shfl_xor(a4, 32);
  w  += __shfl_xor(w, 16);  w  += __shfl_xor(w, 32);
  float tsl = ((const float*)(g_h2b + (size_t)gw * 48 + 40))[hh];
  float es = __expf(lrelu(tsl + sdl));
  const float* h2row = &g_h2[gw * HC2 + c0];  // self loop fp32
  a0 = fmaf(h2row[0], es, a0); a1 = fmaf(h2row[1], es, a1);
  a2 = fmaf(h2row[2], es, a2); a3 = fmaf(h2row[3], es, a3);
  a4 = fmaf(h2row[4], es, a4);
  w += es;
  float inv = 1.f / w;
  float v0 = a0 * inv + bb0, v1 = a1 * inv + bb1, v2 = a2 * inv + bb2;
  float v3 = a3 * inv + bb3, v4 = a4 * inv + bb4;
  // log_softmax over the 80 chs spread across the 16-lane group
  float mx = fmaxf(fmaxf(fmaxf(v0, v1), fmaxf(v2, v3)), v4);
  for (int o = 1; o < 16; o <<= 1) mx = fmaxf(mx, __shfl_xor(mx, o));
  float sp = __expf(v0 - mx) + __expf(v1 - mx) + __expf(v2 - mx) +
             __expf(v3 - mx) + __expf(v4 - mx);
  for (int o = 1; o < 16; o <<= 1) sp += __shfl_xor(sp, o);
  float lse = mx + __logf(sp);
  if (sl == 0) {
    float* op = &out[gw * HC2 + c0];
    op[0] = v0 - lse; op[1] = v1 - lse; op[2] = v2 - lse;
    op[3] = v3 - lse; op[4] = v4 - lse;
  }
}

// ---------------- launch ----------------
extern "C" void kernel_launch(void* const* d_in, const int* in_sizes, int n_in,
                              void* d_out, int out_size, void* d_ws, size_t ws_size,
                              hipStream_t stream) {
  (void)in_sizes; (void)n_in; (void)out_size; (void)d_ws; (void)ws_size;
  const float* x   = (const float*)d_in[0];
  const int*   ei  = (const int*)d_in[1];
  const float* W1  = (const float*)d_in[2];
  const float* as1 = (const float*)d_in[3];
  const float* ad1 = (const float*)d_in[4];
  const float* b1  = (const float*)d_in[5];
  const float* W2  = (const float*)d_in[6];
  const float* as2 = (const float*)d_in[7];
  const float* ad2 = (const float*)d_in[8];
  const float* b2  = (const float*)d_in[9];
  float* out = (float*)d_out;

  // CSR build (radix partition + src-range ordering; shared by both layers)
  p1count_kernel<<<NBLK, 256, 0, stream>>>(ei);
  scn_block_kernel<<<SCNB, 1024, 0, stream>>>();
  scn_add_kernel<<<SCNB, 1024, 0, stream>>>();
  p1scatter_kernel<<<NBLK, 256, 0, stream>>>(ei);
  p2build_kernel<<<NBUK, 1024, 0, stream>>>();

  // layer 1 (gemm1 fuses score/pack epilogue)
  w1cast_kernel<<<64, 256, 0, stream>>>(W1);
  gemm1_kernel<<<1563, 256, 0, stream>>>(x, as1, ad1);
  agg1_kernel<<<25000, 256, 0, stream>>>(b1, as1);

  // layer 2 (gemm2 fuses score/pack epilogue)
  gemm2_kernel<<<2048, 256, 0, stream>>>(W2, as2, ad2);
  agg2_kernel<<<25000, 256, 0, stream>>>(out, b2);
}